// Round 7
// baseline (478.770 us; speedup 1.0000x reference)
//
#include <hip/hip_runtime.h>
#include <hip/hip_bf16.h>
#include <type_traits>
#include <utility>

typedef unsigned short u16;
typedef unsigned int u32;

#define B_ 2
#define T_ 2048
#define C_ 2048
#define H_ 16
#define D_ 128
#define LDQKV 6144  // row stride of qkv [B*T, 3C]

typedef float float4v __attribute__((ext_vector_type(4)));
typedef short short8 __attribute__((ext_vector_type(8)));

__device__ inline u16 f2bf(float f) {
  u32 u = __builtin_bit_cast(u32, f);
  u32 r = u + 0x7fffu + ((u >> 16) & 1u);  // RNE
  return (u16)(r >> 16);
}
__device__ inline float bfbits2f(u16 b) {
  return __builtin_bit_cast(float, (u32)b << 16);
}
// pack two floats to bf16 pair (round-half-up; cheap, used for softmax P)
__device__ inline u32 pack2bf(float a, float b) {
  u32 ua = (__builtin_bit_cast(u32, a) + 0x8000u) >> 16;
  u32 ub = (__builtin_bit_cast(u32, b) + 0x8000u) & 0xffff0000u;
  return ua | ub;
}

#if defined(__HIP_DEVICE_COMPILE__)
typedef __bf16 bf16x8 __attribute__((ext_vector_type(8)));

template <typename V, typename = void>
struct mfma_takes_short : std::false_type {};
template <typename V>
struct mfma_takes_short<V, std::void_t<decltype(__builtin_amdgcn_mfma_f32_16x16x32_bf16(
    std::declval<V>(), std::declval<V>(), std::declval<float4v>(), 0, 0, 0))>>
    : std::true_type {};

template <typename SV>
__device__ inline float4v mfma_bf16(SV a, SV b, float4v c) {
  if constexpr (mfma_takes_short<SV>::value) {
    return __builtin_amdgcn_mfma_f32_16x16x32_bf16(a, b, c, 0, 0, 0);
  } else {
    return __builtin_amdgcn_mfma_f32_16x16x32_bf16(
        __builtin_bit_cast(bf16x8, a), __builtin_bit_cast(bf16x8, b), c, 0, 0, 0);
  }
}

// Async global->LDS, 16B/lane. LDS dest = wave-uniform base + lane*16.
__device__ inline void async16(u16* lds, const u16* g) {
  typedef __attribute__((address_space(3))) void lds_void;
  typedef __attribute__((address_space(1))) const void g_void;
  __builtin_amdgcn_global_load_lds((g_void*)g, (lds_void*)lds, 16, 0, 0);
}
#endif

// ---------------- merged pre-cast kernel ----------------
// blocks [0,8192): cast x -> xb (bf16)
// blocks [8192,20480): castT wqkv [2048,6144] -> wqkvT [6144,2048]
// blocks [20480,24576): castT wout [2048,2048] -> woutT [2048,2048]
__global__ __launch_bounds__(256) void prep_all(const float* __restrict__ x,
                                                u16* __restrict__ xb,
                                                const float* __restrict__ wqkv,
                                                u16* __restrict__ wqkvT,
                                                const float* __restrict__ wout,
                                                u16* __restrict__ woutT) {
  __shared__ float tile[32][33];
  const int bid = blockIdx.x;
  const int t = threadIdx.x;
  if (bid < 8192) {
    int i = (bid * 256 + t) * 4;
    float4 v = *(const float4*)(x + i);
    alignas(8) u16 o[4] = {f2bf(v.x), f2bf(v.y), f2bf(v.z), f2bf(v.w)};
    *(uint2*)(xb + i) = *(const uint2*)o;
    return;
  }
  const float* src;
  u16* dst;
  int bx, by, R, Cc;
  if (bid < 20480) {
    int b2 = bid - 8192;
    bx = b2 % 192;
    by = b2 / 192;
    src = wqkv;
    dst = wqkvT;
    R = 2048;
    Cc = 6144;
  } else {
    int b3 = bid - 20480;
    bx = b3 & 63;
    by = b3 >> 6;
    src = wout;
    dst = woutT;
    R = 2048;
    Cc = 2048;
  }
  const int r0 = by * 32, c0 = bx * 32;
  const int lr = t >> 3, lc = (t & 7) * 4;
  float4 v = *(const float4*)(src + (size_t)(r0 + lr) * Cc + c0 + lc);
  tile[lr][lc + 0] = v.x;
  tile[lr][lc + 1] = v.y;
  tile[lr][lc + 2] = v.z;
  tile[lr][lc + 3] = v.w;
  __syncthreads();
  alignas(8) u16 o[4];
#pragma unroll
  for (int j = 0; j < 4; ++j) o[j] = f2bf(tile[lc + j][lr]);
  *(uint2*)(dst + (size_t)(c0 + lr) * R + r0 + lc) = *(const uint2*)o;
}

// ---------------- merged rope + vT kernel ----------------
// blocks [0,16384): in-place RoPE on q,k columns (q scaled by qscale)
// blocks [16384,18432): V columns -> Vt [BH,128,2048] per-head transpose
__global__ __launch_bounds__(256) void rope_vt(u16* __restrict__ qkv,
                                               u16* __restrict__ Vt, float qscale) {
  __shared__ u16 lt[64][72];
  const int tid = threadIdx.x;
  const int bid = blockIdx.x;
  if (bid < 16384) {
    int idx = bid * 256 + tid;
    int d = idx & 63;
    int h = (idx >> 6) & 15;
    int t = (idx >> 10) & 2047;
    int b = idx >> 21;
    size_t row = (size_t)(b * T_ + t) * LDQKV;
    u16* qp = qkv + row + h * 128;
    u16* kp = qkv + row + C_ + h * 128;
    float q1 = bfbits2f(qp[d]);
    float q2 = bfbits2f(qp[d + 64]);
    float k1 = bfbits2f(kp[d]);
    float k2 = bfbits2f(kp[d + 64]);
    float invf = exp2f((float)d * -0.20762050593046012f);
    float fr = (float)t * invf;
    float sn, cs;
    sincosf(fr, &sn, &cs);
    qp[d] = f2bf((q1 * cs - q2 * sn) * qscale);
    qp[d + 64] = f2bf((q2 * cs + q1 * sn) * qscale);
    kp[d] = f2bf(k1 * cs - k2 * sn);
    kp[d + 64] = f2bf(k2 * cs + k1 * sn);
    return;
  }
  int b2 = bid - 16384;
  const int bh = b2 & 31;         // 32
  const int tt = (b2 >> 5) & 31;  // 32 t-tiles of 64
  const int dd = b2 >> 10;        // 2 d-tiles of 64
  const int b = bh >> 4, h = bh & 15;
  const int r = tid >> 2;
  const int c4 = (tid & 3) * 16;
  const u16* src = qkv + ((size_t)(b * T_ + tt * 64 + r)) * LDQKV + 2 * C_ + h * 128 + dd * 64 + c4;
  *(uint4*)&lt[r][c4] = *(const uint4*)src;
  *(uint4*)&lt[r][c4 + 8] = *(const uint4*)(src + 8);
  __syncthreads();
  alignas(16) u16 o[16];
#pragma unroll
  for (int j = 0; j < 16; ++j) o[j] = lt[c4 + j][r];
  u16* dst = Vt + ((size_t)(bh * 128 + dd * 64 + r)) * 2048 + tt * 64 + c4;
  *(uint4*)dst = *(const uint4*)o;
  *(uint4*)(dst + 8) = *(const uint4*)(o + 8);
}

// ---------------- 256x256 8-phase GEMM (T1+T2+T3+T4+T5) ----------------
// A [M,K] bf16 rm, BT [N,K] bf16 rm. M%256==0, N%256==0, K%128==0.
// 512 thr / 8 waves (2M x 4N); per-wave 128x64 out; BK=64, 2 K-tiles/iter.
// LDS 128 KiB: 2 bufs x (A 256x64 + B 256x64). Chunk swizzle: logical 8-elem
// chunk cc of row R stored at chunk cc^(R&7) -> conflict-free ds_read_b128,
// and global_load_lds sources are pre-swizzled to match (rule #21).
// v1 schedule (best measured; staging-traffic bound — see session notes).
template <bool CF32>
__global__ __launch_bounds__(512, 2) void gemm256_bt(const u16* __restrict__ A,
                                                     const u16* __restrict__ BT,
                                                     void* __restrict__ Cp,
                                                     int K, int lda, int ldbt, int ldc,
                                                     int nbx) {
#if defined(__HIP_DEVICE_COMPILE__)
  __shared__ alignas(16) u16 As[2][256 * 64];
  __shared__ alignas(16) u16 Bs[2][256 * 64];
  const int tid = threadIdx.x;
  const int lane = tid & 63;
  const int w = tid >> 6;             // 0..7
  const int wm = w >> 2, wn = w & 3;  // wave tile: rows wm*128, cols wn*64
  const int ml = lane & 15, qd = lane >> 4;
  // XCD-aware bijective swizzle (gridDim.x % 8 == 0 guaranteed by launch)
  const int nwg = gridDim.x;
  const int cpx = nwg >> 3;
  const int swz = (blockIdx.x & 7) * cpx + (blockIdx.x >> 3);
  const int by = swz / nbx, bx = swz - by * nbx;
  const int m0 = by * 256, n0 = bx * 256;
  // staging lane decomposition: each async16 issue covers 8 rows x 128B
  const int rowoff = lane >> 3;                  // row within 8-row group
  const int chunk = ((lane & 7) ^ rowoff) * 8;   // pre-swizzled source chunk (u16)
  // per-wave 8-row-group bases for each half-tile (2 issues/wave/half-tile)
  int rA0[2], rA1[2], rB0[2], rB1[2];
#pragma unroll
  for (int j = 0; j < 2; ++j) {
    int g = w * 2 + j;
    rA0[j] = (g >> 3) * 128 + (g & 7) * 8;       // A rows with bit6==0
    rA1[j] = (g >> 3) * 128 + 64 + (g & 7) * 8;  // A rows with bit6==1
    rB0[j] = (g >> 2) * 64 + (g & 3) * 8;        // B rows with bit5==0
    rB1[j] = (g >> 2) * 64 + 32 + (g & 3) * 8;   // B rows with bit5==1
  }
  const int ntiles = K >> 6;
  const int niter = ntiles >> 1;

#define STG_A(bufi, h, kt)                                                       \
  do {                                                                           \
    async16(&As[bufi][rA##h[0] * 64],                                            \
            A + (size_t)(m0 + rA##h[0] + rowoff) * lda + (kt) * 64 + chunk);     \
    async16(&As[bufi][rA##h[1] * 64],                                            \
            A + (size_t)(m0 + rA##h[1] + rowoff) * lda + (kt) * 64 + chunk);     \
  } while (0)
#define STG_B(bufi, h, kt)                                                       \
  do {                                                                           \
    async16(&Bs[bufi][rB##h[0] * 64],                                            \
            BT + (size_t)(n0 + rB##h[0] + rowoff) * ldbt + (kt) * 64 + chunk);   \
    async16(&Bs[bufi][rB##h[1] * 64],                                            \
            BT + (size_t)(n0 + rB##h[1] + rowoff) * ldbt + (kt) * 64 + chunk);   \
  } while (0)
#define LDA8(bufi, mh)                                                           \
  do {                                                                           \
    _Pragma("unroll") for (int mt_ = 0; mt_ < 4; ++mt_)                          \
    _Pragma("unroll") for (int ks_ = 0; ks_ < 2; ++ks_)                          \
      a[mt_][ks_] = *(const short8*)&As[bufi][                                   \
          (wm * 128 + (mh) * 64 + mt_ * 16 + ml) * 64 +                          \
          (((qd + ks_ * 4) ^ (ml & 7)) * 8)];                                    \
  } while (0)
#define LDB4(bufi, nh)                                                           \
  do {                                                                           \
    _Pragma("unroll") for (int nt_ = 0; nt_ < 2; ++nt_)                          \
    _Pragma("unroll") for (int ks_ = 0; ks_ < 2; ++ks_)                          \
      b[nt_][ks_] = *(const short8*)&Bs[bufi][                                   \
          (wn * 64 + (nh) * 32 + nt_ * 16 + ml) * 64 +                           \
          (((qd + ks_ * 4) ^ (ml & 7)) * 8)];                                    \
  } while (0)
#define MMA16(mh, nh)                                                            \
  do {                                                                           \
    __builtin_amdgcn_s_setprio(1);                                               \
    _Pragma("unroll") for (int ks_ = 0; ks_ < 2; ++ks_)                          \
    _Pragma("unroll") for (int mt_ = 0; mt_ < 4; ++mt_)                          \
    _Pragma("unroll") for (int nt_ = 0; nt_ < 2; ++nt_)                          \
      acc[(mh) * 4 + mt_][(nh) * 2 + nt_] = mfma_bf16(                           \
          a[mt_][ks_], b[nt_][ks_], acc[(mh) * 4 + mt_][(nh) * 2 + nt_]);        \
    __builtin_amdgcn_s_setprio(0);                                               \
  } while (0)
#define BAR __builtin_amdgcn_s_barrier()
#define LGKM0 asm volatile("s_waitcnt lgkmcnt(0)" ::: "memory")
#define LGKM8 asm volatile("s_waitcnt lgkmcnt(8)" ::: "memory")
#define VM4 asm volatile("s_waitcnt vmcnt(4)" ::: "memory")

  float4v acc[8][4] = {};
  short8 a[4][2], b[2][2];

  // prologue: tile0 fully + tile1 front halves; vmcnt(4) = tile0 landed
  STG_A(0, 0, 0);
  STG_B(0, 0, 0);
  STG_A(0, 1, 0);
  STG_B(0, 1, 0);
  STG_A(1, 0, 1);
  STG_B(1, 0, 1);
  VM4;
  BAR;

  for (int i = 0; i < niter; ++i) {
    const int tb = 2 * i + 1;
    // clamp prefetch tiles in last iter: keeps vmcnt accounting uniform;
    // clamped stages write only dead LDS regions.
    const int t2 = (2 * i + 2 < ntiles) ? 2 * i + 2 : ntiles - 1;
    const int t3 = (2 * i + 3 < ntiles) ? 2 * i + 3 : ntiles - 1;
    // ---- P1: quad(0,0) of tile 2i (buf0) ----
    LDA8(0, 0);
    LDB4(0, 0);
    STG_A(1, 1, tb);
    LGKM8;
    BAR; LGKM0; MMA16(0, 0); BAR;
    // ---- P2: quad(0,1) ----
    LDB4(0, 1);
    STG_B(1, 1, tb);
    BAR; LGKM0; MMA16(0, 1); BAR;
    // ---- P3: quad(1,0) ----
    LDA8(0, 1);
    LDB4(0, 0);
    STG_A(0, 0, t2);
    LGKM8;
    BAR; LGKM0; MMA16(1, 0); BAR;
    // ---- P4: quad(1,1); gate tile 2i+1 (covers through P2) ----
    LDB4(0, 1);
    STG_B(0, 0, t2);
    VM4;
    BAR; LGKM0; MMA16(1, 1); BAR;
    // ---- P5: quad(0,0) of tile 2i+1 (buf1) ----
    LDA8(1, 0);
    LDB4(1, 0);
    STG_A(0, 1, t2);
    LGKM8;
    BAR; LGKM0; MMA16(0, 0); BAR;
    // ---- P6: quad(0,1) ----
    LDB4(1, 1);
    STG_B(0, 1, t2);
    BAR; LGKM0; MMA16(0, 1); BAR;
    // ---- P7: quad(1,0) ----
    LDA8(1, 1);
    LDB4(1, 0);
    STG_A(1, 0, t3);
    LGKM8;
    BAR; LGKM0; MMA16(1, 0); BAR;
    // ---- P8: quad(1,1); gate tile 2i+2 (covers through P6) ----
    LDB4(1, 1);
    STG_B(1, 0, t3);
    VM4;
    BAR; LGKM0; MMA16(1, 1); BAR;
  }

#pragma unroll
  for (int mt = 0; mt < 8; ++mt) {
#pragma unroll
    for (int nt = 0; nt < 4; ++nt) {
#pragma unroll
      for (int r = 0; r < 4; ++r) {
        int row = m0 + wm * 128 + mt * 16 + qd * 4 + r;
        int col = n0 + wn * 64 + nt * 16 + ml;
        if constexpr (CF32) {
          ((float*)Cp)[(size_t)row * ldc + col] = acc[mt][nt][r];
        } else {
          ((u16*)Cp)[(size_t)row * ldc + col] = f2bf(acc[mt][nt][r]);
        }
      }
    }
  }
#undef STG_A
#undef STG_B
#undef LDA8
#undef LDB4
#undef MMA16
#undef BAR
#undef LGKM0
#undef LGKM8
#undef VM4
#endif
}

// ---------------- m97-style GEMM ----------------
template <bool CF32>
__global__ __launch_bounds__(256) void gemm_bt(const u16* __restrict__ A,
                                               const u16* __restrict__ BT,
                                               void* __restrict__ Cp,
                                               int K, int lda, int ldbt, int ldc) {
#if defined(__HIP_DEVICE_COMPILE__)
  __shared__ u16 As[4096];  // 128x32 [m][k] linear
  __shared__ u16 Bs[4096];  // 128x32 [n][k] linear
  const int tid = threadIdx.x;
  const int lane = tid & 63;
  const int w = tid >> 6;
  const int wm = w & 1, wn = w >> 1;
  const int ml = lane & 15, qd = lane >> 4;
  const int m0 = blockIdx.y * 128, n0 = blockIdx.x * 128;
  const int sm = lane >> 2, sk = (lane & 3) * 8;
  const u16* gA[2];
  const u16* gB[2];
  u16 *lA[2], *lB[2];
#pragma unroll
  for (int r = 0; r < 2; ++r) {
    int seg = r * 4 + w;
    gA[r] = A + (size_t)(m0 + seg * 16 + sm) * lda + sk;
    gB[r] = BT + (size_t)(n0 + seg * 16 + sm) * ldbt + sk;
    lA[r] = As + seg * 512;
    lB[r] = Bs + seg * 512;
  }
  float4v acc[4][4] = {};
  for (int kk = 0; kk < K; kk += 32) {
    __syncthreads();
    async16(lA[0], gA[0] + kk);
    async16(lA[1], gA[1] + kk);
    async16(lB[0], gB[0] + kk);
    async16(lB[1], gB[1] + kk);
    __syncthreads();
    short8 a[4], b[4];
#pragma unroll
    for (int mt = 0; mt < 4; ++mt)
      a[mt] = *(const short8*)(As + (wm * 64 + mt * 16 + ml) * 32 + qd * 8);
#pragma unroll
    for (int nt = 0; nt < 4; ++nt)
      b[nt] = *(const short8*)(Bs + (wn * 64 + nt * 16 + ml) * 32 + qd * 8);
#pragma unroll
    for (int mt = 0; mt < 4; ++mt)
#pragma unroll
      for (int nt = 0; nt < 4; ++nt) acc[mt][nt] = mfma_bf16(a[mt], b[nt], acc[mt][nt]);
  }
#pragma unroll
  for (int mt = 0; mt < 4; ++mt) {
#pragma unroll
    for (int nt = 0; nt < 4; ++nt) {
#pragma unroll
      for (int r = 0; r < 4; ++r) {
        int row = m0 + wm * 64 + mt * 16 + qd * 4 + r;
        int col = n0 + wn * 64 + nt * 16 + ml;
        if constexpr (CF32) {
          ((float*)Cp)[(size_t)row * ldc + col] = acc[mt][nt][r];
        } else {
          ((u16*)Cp)[(size_t)row * ldc + col] = f2bf(acc[mt][nt][r]);
        }
      }
    }
  }
#endif
}

// ---------------- fallback GEMM ----------------
template <bool AF32, bool BF32, bool CF32>
__global__ __launch_bounds__(256) void gemm_mixed(const void* __restrict__ Ap,
                                                  const void* __restrict__ Bp,
                                                  void* __restrict__ Cp,
                                                  int M, int N, int K,
                                                  int lda, int ldb, int ldc) {
#if defined(__HIP_DEVICE_COMPILE__)
  __shared__ u16 As[64][40];
  __shared__ u16 Bs[64][40];
  const int tid = threadIdx.x;
  const int lane = tid & 63;
  const int w = tid >> 6;
  const int m0 = blockIdx.y * 64;
  const int n0 = blockIdx.x * 64;
  const int arow = tid >> 2, acol = (tid & 3) * 8;
  const int brow = tid >> 3, bcol = (tid & 7) * 8;
  const int ml = lane & 15, qd = lane >> 4;
  float4v acc[4] = {};
  for (int kk = 0; kk < K; kk += 32) {
    __syncthreads();
    if constexpr (AF32) {
      const float* A = (const float*)Ap;
      const float* src = A + (size_t)(m0 + arow) * lda + (kk + acol);
      float4 f0 = *(const float4*)src;
      float4 f1 = *(const float4*)(src + 4);
      alignas(16) u16 tmp[8] = {f2bf(f0.x), f2bf(f0.y), f2bf(f0.z), f2bf(f0.w),
                                f2bf(f1.x), f2bf(f1.y), f2bf(f1.z), f2bf(f1.w)};
      *(uint4*)(&As[arow][acol]) = *(const uint4*)tmp;
    } else {
      const u16* A = (const u16*)Ap;
      *(uint4*)(&As[arow][acol]) = *(const uint4*)(A + (size_t)(m0 + arow) * lda + (kk + acol));
    }
    if constexpr (BF32) {
      const float* Bm = (const float*)Bp;
      const float* src = Bm + (size_t)(kk + brow) * ldb + (n0 + bcol);
      float4 f0 = *(const float4*)src;
      float4 f1 = *(const float4*)(src + 4);
      float fv[8] = {f0.x, f0.y, f0.z, f0.w, f1.x, f1.y, f1.z, f1.w};
#pragma unroll
      for (int i = 0; i < 8; ++i) Bs[bcol + i][brow] = f2bf(fv[i]);
    } else {
      const u16* Bm = (const u16*)Bp;
      uint4 bv = *(const uint4*)(Bm + (size_t)(kk + brow) * ldb + (n0 + bcol));
      const u16* bsp = (const u16*)&bv;
#pragma unroll
      for (int i = 0; i < 8; ++i) Bs[bcol + i][brow] = bsp[i];
    }
    __syncthreads();
    short8 af = *(const short8*)(&As[w * 16 + ml][qd * 8]);
#pragma unroll
    for (int nt = 0; nt < 4; ++nt) {
      short8 bf = *(const short8*)(&Bs[nt * 16 + ml][qd * 8]);
      acc[nt] = mfma_bf16(af, bf, acc[nt]);
    }
  }
#pragma unroll
  for (int nt = 0; nt < 4; ++nt) {
#pragma unroll
    for (int r = 0; r < 4; ++r) {
      int row = m0 + w * 16 + qd * 4 + r;
      int col = n0 + nt * 16 + ml;
      if constexpr (CF32) {
        ((float*)Cp)[(size_t)row * ldc + col] = acc[nt][r];
      } else {
        ((u16*)Cp)[(size_t)row * ldc + col] = f2bf(acc[nt][r]);
      }
    }
  }
#endif
}

// In-place RoPE on qkv [B,T,3C] bf16; q additionally scaled by qscale.
// (fallback path only; main path uses rope_vt)
__global__ __launch_bounds__(256) void rope_inplace(u16* __restrict__ qkv, float qscale) {
  int idx = blockIdx.x * 256 + threadIdx.x;
  int d = idx & 63;
  int h = (idx >> 6) & 15;
  int t = (idx >> 10) & 2047;
  int b = idx >> 21;
  size_t row = (size_t)(b * T_ + t) * LDQKV;
  u16* qp = qkv + row + h * 128;
  u16* kp = qkv + row + C_ + h * 128;
  float q1 = bfbits2f(qp[d]);
  float q2 = bfbits2f(qp[d + 64]);
  float k1 = bfbits2f(kp[d]);
  float k2 = bfbits2f(kp[d + 64]);
  float invf = exp2f((float)d * -0.20762050593046012f);
  float fr = (float)t * invf;
  float sn, cs;
  sincosf(fr, &sn, &cs);
  qp[d] = f2bf((q1 * cs - q2 * sn) * qscale);
  qp[d + 64] = f2bf((q2 * cs + q1 * sn) * qscale);
  kp[d] = f2bf(k1 * cs - k2 * sn);
  kp[d + 64] = f2bf(k2 * cs + k1 * sn);
}

// MFMA flash attention v5: single-buffered K/V staging, 3 blocks/CU.
// Occupancy lever: dbuf was measured NEUTRAL (r2 vs r3) so trade LDS for
// waves — 16K (kS) + 16K (vS) + 10K (pS) = 42 KiB -> 3 blocks/CU
// (__launch_bounds__(256,3) caps VGPR at 170 so it materializes).
// 3 waves/SIMD hide the serial softmax/shfl/LDS-latency chains that kept
// MfmaUtil ~10% at 2 blocks/CU. Flow per chunk: stage -> vmcnt(0) ->
// barrier -> compute -> barrier (rounds 0-2 validated structure).
// NOTE: exp2-domain/defer-max/setprio variants measured NEGATIVE (-18us,
// round 5) — do not re-add without within-probe A/B.
__global__ __launch_bounds__(256, 3) void attn_fwd2(u16* __restrict__ qkv,
                                                    const u16* __restrict__ Vt) {
#if defined(__HIP_DEVICE_COMPILE__)
  __shared__ alignas(16) u16 kS[64 * 128];   // [key][d], swizzled slots
  __shared__ alignas(16) u16 vS[128 * 64];   // [d][key], swizzled slots
  __shared__ alignas(16) u16 pS[4][32][40];  // per-wave P [q][32 keys], +8 pad
  const int tid = threadIdx.x;
  const int lane = tid & 63;
  const int w = tid >> 6;
  const int ml = lane & 15, qd = lane >> 4;
  const int gx = blockIdx.x;
  const int half = gx >> 8, rem = gx & 255;
  const int bh = rem >> 3, q3 = rem & 7;
  const int qt = half ? q3 : (15 - q3);  // pair long+short tiles across halves
  const int b = bh >> 4, h = bh & 15;
  const int hc = h * 128;
  const int m0 = qt * 128;
  const size_t rb = (size_t)(b * T_);
  // Q B-frags in registers for whole block: qf[qtile][k4]; lane n=ml -> q-row
  short8 qf[2][4];
#pragma unroll
  for (int m = 0; m < 2; ++m) {
    const u16* qp = qkv + (rb + m0 + w * 32 + m * 16 + ml) * LDQKV + hc;
#pragma unroll
    for (int k4 = 0; k4 < 4; ++k4) qf[m][k4] = *(const short8*)(qp + k4 * 32 + qd * 8);
  }
  float4v acc[2][8] = {};
  float mi[2] = {-1.0e30f, -1.0e30f}, li[2] = {0.f, 0.f};
  const int nchunk = 2 * qt + 2;
  // staging decode (closed forms)
  const int krow0 = w * 16 + qd;                    // + i*4
  const int vd0 = w * 32 + (lane >> 3);             // + i*8
  const int vsegoff = ((lane & 7) ^ (lane >> 3)) * 8;
  const size_t vtbase = ((size_t)bh * 128) * 2048;

#define STAGE(cc)                                                            \
  do {                                                                       \
    _Pragma("unroll") for (int i_ = 0; i_ < 4; ++i_) {                       \
      int key_ = krow0 + i_ * 4;                                             \
      int seg_ = (ml ^ (i_ * 4 + qd)) * 8;                                   \
      async16(kS + (w * 4 + i_) * 512,                                       \
              qkv + (rb + (cc) * 64 + key_) * LDQKV + C_ + hc + seg_);       \
    }                                                                        \
    _Pragma("unroll") for (int i_ = 0; i_ < 4; ++i_) {                       \
      int d_ = vd0 + i_ * 8;                                                 \
      async16(vS + (w * 4 + i_) * 512,                                       \
              Vt + vtbase + (size_t)d_ * 2048 + (cc) * 64 + vsegoff);        \
    }                                                                        \
  } while (0)

  for (int c = 0; c < nchunk; ++c) {
    // all waves done reading the previous chunk before overwrite
    __syncthreads();
    STAGE(c);
    asm volatile("s_waitcnt vmcnt(0)" ::: "memory");
    __syncthreads();
    if (c * 64 > m0 + w * 32 + 31) continue;  // all keys future for this wave
    // ---- S^T = K Q^T : s[kt][qtile], C row=key(qd*4+r), col=q(ml) ----
    float4v s[4][2] = {};
#pragma unroll
    for (int kt = 0; kt < 4; ++kt) {
#pragma unroll
      for (int k4 = 0; k4 < 4; ++k4) {
        short8 kf = *(const short8*)(kS + ((kt * 16 + ml) * 16 + ((k4 * 4 + qd) ^ ml)) * 8);
        s[kt][0] = mfma_bf16(kf, qf[0][k4], s[kt][0]);
        s[kt][1] = mfma_bf16(kf, qf[1][k4], s[kt][1]);
      }
    }
    const bool domask = (c * 64 + 63) > (m0 + w * 32);
    float alpha[2];
#pragma unroll
    for (int m = 0; m < 2; ++m) {
      int qrow = m0 + w * 32 + m * 16 + ml;
      if (domask) {
#pragma unroll
        for (int kt = 0; kt < 4; ++kt)
#pragma unroll
          for (int r = 0; r < 4; ++r) {
            int key = c * 64 + kt * 16 + qd * 4 + r;
            if (key > qrow) s[kt][m][r] = -1.0e30f;
          }
      }
      float mx = -1.0e30f;
#pragma unroll
      for (int kt = 0; kt < 4; ++kt)
#pragma unroll
        for (int r = 0; r < 4; ++r) mx = fmaxf(mx, s[kt][m][r]);
      mx = fmaxf(mx, __shfl_xor(mx, 16, 64));
      mx = fmaxf(mx, __shfl_xor(mx, 32, 64));
      float mnew = fmaxf(mi[m], mx);
      float a = __expf(mi[m] - mnew);
      float sm = 0.f;
#pragma unroll
      for (int kt = 0; kt < 4; ++kt)
#pragma unroll
        for (int r = 0; r < 4; ++r) {
          float p = __expf(s[kt][m][r] - mnew);
          s[kt][m][r] = p;
          sm += p;
        }
      sm += __shfl_xor(sm, 16, 64);
      sm += __shfl_xor(sm, 32, 64);
      li[m] = li[m] * a + sm;
      mi[m] = mnew;
      alpha[m] = a;
    }
    // rescale O (alpha lives at lane ml=q'; broadcast to rows qd*4+r)
#pragma unroll
    for (int m = 0; m < 2; ++m) {
#pragma unroll
      for (int r = 0; r < 4; ++r) {
        float aq = __shfl(alpha[m], qd * 4 + r, 64);
#pragma unroll
        for (int dt = 0; dt < 8; ++dt) acc[m][dt][r] *= aq;
      }
    }
    // ---- O += P V, in two 32-key halves through the small pS buffer ----
#pragma unroll
    for (int k2 = 0; k2 < 2; ++k2) {
#pragma unroll
      for (int m = 0; m < 2; ++m) {
#pragma unroll
        for (int ktl = 0; ktl < 2; ++ktl) {
          int kt = k2 * 2 + ktl;
          uint2 pk;
          pk.x = pack2bf(s[kt][m][0], s[kt][m][1]);
          pk.y = pack2bf(s[kt][m][2], s[kt][m][3]);
          *(uint2*)&pS[w][m * 16 + ml][ktl * 16 + qd * 4] = pk;
        }
      }
      short8 pa0 = *(const short8*)&pS[w][ml][qd * 8];
      short8 pa1 = *(const short8*)&pS[w][16 + ml][qd * 8];
#pragma unroll
      for (int dt = 0; dt < 8; ++dt) {
        int d = dt * 16 + ml;
        short8 vf = *(const short8*)(vS + (d * 8 + ((k2 * 4 + qd) ^ (ml & 7))) * 8);
        acc[0][dt] = mfma_bf16(pa0, vf, acc[0][dt]);
        acc[1][dt] = mfma_bf16(pa1, vf, acc[1][dt]);
      }
    }
  }
#undef STAGE
  // ---- epilogue: O/l -> Q cols of qkv ----
#pragma unroll
  for (int m = 0; m < 2; ++m) {
#pragma unroll
    for (int r = 0; r < 4; ++r) {
      float inv = 1.0f / __shfl(li[m], qd * 4 + r, 64);
      size_t row = rb + m0 + w * 32 + m * 16 + qd * 4 + r;
#pragma unroll
      for (int dt = 0; dt < 8; ++dt)
        qkv[row * LDQKV + hc + dt * 16 + ml] = f2bf(acc[m][dt][r] * inv);
    }
  }
#endif
}

// Old flash attention (fallback path; expects unscaled Q).
__global__ __launch_bounds__(256, 2) void attn_fwd(u16* __restrict__ qkv) {
#if defined(__HIP_DEVICE_COMPILE__)
  __shared__ alignas(16) u16 ks[64][136];
  __shared__ alignas(16) u16 vt[128][72];
  __shared__ alignas(16) u16 pb[4][32][72];
  const int tid = threadIdx.x;
  const int lane = tid & 63;
  const int w = tid >> 6;
  const int ml = lane & 15, qd = lane >> 4;
  const int gx = blockIdx.x;
  const int half = gx >> 8;
  const int rem = gx & 255;
  const int bh = rem >> 3;
  const int q3 = rem & 7;
  const int qt = half ? q3 : (15 - q3);
  const int b = bh >> 4, h = bh & 15;
  const int hc = h * 128;
  const int m0 = qt * 128;
  const size_t rb = (size_t)(b * T_);
  short8 qf[2][4];
#pragma unroll
  for (int m = 0; m < 2; ++m) {
    const u16* qp = qkv + (rb + m0 + w * 32 + m * 16 + ml) * LDQKV + hc;
#pragma unroll
    for (int k4 = 0; k4 < 4; ++k4) qf[m][k4] = *(const short8*)(qp + k4 * 32 + qd * 8);
  }
  float4v acc[2][8] = {};
  float mi[2][4], li[2][4];
#pragma unroll
  for (int m = 0; m < 2; ++m)
#pragma unroll
    for (int r = 0; r < 4; ++r) { mi[m][r] = -1.0e30f; li[m][r] = 0.f; }
  const float scale = 0.08838834764831845f;
  const int srow = tid >> 2;
  const int scol = (tid & 3) * 32;
  const int nchunk = 2 * qt + 2;
  for (int c = 0; c < nchunk; ++c) {
    __syncthreads();
    {
      const u16* kp = qkv + (rb + c * 64 + srow) * LDQKV + C_ + hc + scol;
      const u16* vp = qkv + (rb + c * 64 + srow) * LDQKV + 2 * C_ + hc + scol;
#pragma unroll
      for (int i = 0; i < 4; ++i)
        *(uint4*)&ks[srow][scol + i * 8] = *(const uint4*)(kp + i * 8);
#pragma unroll
      for (int i = 0; i < 4; ++i) {
        uint4 vv = *(const uint4*)(vp + i * 8);
        const u16* e = (const u16*)&vv;
#pragma unroll
        for (int t = 0; t < 8; ++t) vt[scol + i * 8 + t][srow] = e[t];
      }
    }
    __syncthreads();
    if (c * 64 > m0 + w * 32 + 31) continue;
    float4v s[2][4] = {};
#pragma unroll
    for (int t = 0; t < 4; ++t) {
#pragma unroll
      for (int k4 = 0; k4 < 4; ++k4) {
        short8 bf = *(const short8*)(&ks[t * 16 + ml][k4 * 32 + qd * 8]);
        s[0][t] = mfma_bf16(qf[0][k4], bf, s[0][t]);
        s[1][t] = mfma_bf16(qf[1][k4], bf, s[1][t]);
      }
    }
    const bool domask = (c * 64 + 63) > (m0 + w * 32);
#pragma unroll
    for (int m = 0; m < 2; ++m) {
      float al[4];
#pragma unroll
      for (int r = 0; r < 4; ++r) {
        float x0 = s[m][0][r] * scale;
        float x1 = s[m][1][r] * scale;
        float x2 = s[m][2][r] * scale;
        float x3 = s[m][3][r] * scale;
        if (domask) {
          int row = m0 + w * 32 + m * 16 + qd * 4 + r;
          int j0 = c * 64 + ml;
          if (j0 > row) x0 = -1.0e30f;
          if (j0 + 16 > row) x1 = -1.0e30f;
          if (j0 + 32 > row) x2 = -1.0e30f;
          if (j0 + 48 > row) x3 = -1.0e30f;
        }
        float mx = fmaxf(fmaxf(x0, x1), fmaxf(x2, x3));
        mx = fmaxf(mx, __shfl_xor(mx, 1));
        mx = fmaxf(mx, __shfl_xor(mx, 2));
        mx = fmaxf(mx, __shfl_xor(mx, 4));
        mx = fmaxf(mx, __shfl_xor(mx, 8));
        float mnew = fmaxf(mi[m][r], mx);
        float a = __expf(mi[m][r] - mnew);
        float p0 = __expf(x0 - mnew);
        float p1 = __expf(x1 - mnew);
        float p2 = __expf(x2 - mnew);
        float p3 = __expf(x3 - mnew);
        float sm = p0 + p1 + p2 + p3;
        sm += __shfl_xor(sm, 1);
        sm += __shfl_xor(sm, 2);
        sm += __shfl_xor(sm, 4);
        sm += __shfl_xor(sm, 8);
        li[m][r] = li[m][r] * a + sm;
        mi[m][r] = mnew;
        al[r] = a;
        int prow = m * 16 + qd * 4 + r;
        pb[w][prow][ml] = f2bf(p0);
        pb[w][prow][16 + ml] = f2bf(p1);
        pb[w][prow][32 + ml] = f2bf(p2);
        pb[w][prow][48 + ml] = f2bf(p3);
      }
#pragma unroll
      for (int d = 0; d < 8; ++d) {
        acc[m][d][0] *= al[0];
        acc[m][d][1] *= al[1];
        acc[m][d][2] *= al[2];
        acc[m][d][3] *= al[3];
      }
    }
#pragma unroll
    for (int k2 = 0; k2 < 2; ++k2) {
      short8 pa0 = *(const short8*)(&pb[w][ml][k2 * 32 + qd * 8]);
      short8 pa1 = *(const short8*)(&pb[w][16 + ml][k2 * 32 + qd * 8]);
#pragma unroll
      for (int d = 0; d < 8; ++d) {
        short8 vf = *(const short8*)(&vt[d * 16 + ml][k2 * 32 + qd * 8]);
        acc[0][d] = mfma_bf16(pa0, vf, acc[0][d]);
        acc[1][d] = mfma_bf16(pa1, vf, acc[1][d]);
      }
    }
  }
#pragma unroll
  for (int m = 0; m < 2; ++m) {
#pragma unroll
    for (int r = 0; r < 4; ++r) {
      float inv = 1.0f / li[m][r];
      size_t row = rb + m0 + w * 32 + m * 16 + qd * 4 + r;
#pragma unroll
      for (int d = 0; d < 8; ++d)
        qkv[row * LDQKV + hc + d * 16 + ml] = f2bf(acc[m][d][r] * inv);
    }
  }
#endif
}

extern "C" void kernel_launch(void* const* d_in, const int* in_sizes, int n_in,
                              void* d_out, int out_size, void* d_ws, size_t ws_size,
                              hipStream_t stream) {
  const float* x = (const float*)d_in[0];     // [B,T,C] fp32
  const float* wqkv = (const float*)d_in[1];  // [C,3C] fp32
  const float* wout = (const float*)d_in[2];  // [C,C] fp32
  float* out = (float*)d_out;                 // [B,T,C] fp32
  char* ws = (char*)d_ws;
  u16* qkv = (u16*)ws;  // [4096, 6144] bf16 = 48 MB; Q cols reused as Y

  const size_t MB = 1024 * 1024;
  if (ws_size >= 96 * MB) {
    u16* xb = (u16*)(ws + 48 * MB);     // [4096,2048] bf16, 16 MB
    u16* wqkvT = (u16*)(ws + 64 * MB);  // [6144,2048] bf16, 24 MB
    u16* Vt = (u16*)(ws + 64 * MB);     // [32,128,2048] bf16, 16 MB (reuses wqkvT after GEMM1)
    u16* woutT = (u16*)(ws + 88 * MB);  // [2048,2048] bf16, 8 MB
    // merged pre-casts: x->xb, wqkv->wqkvT, wout->woutT (one launch)
    prep_all<<<dim3(24576), dim3(256), 0, stream>>>(x, xb, wqkv, wqkvT, wout, woutT);
    // GEMM1: 256x256 8-phase pipeline; grid = (4096/256)*(6144/256) = 384 (%8==0)
    gemm256_bt<false><<<dim3(384), dim3(512), 0, stream>>>(
        xb, wqkvT, qkv, 2048, 2048, 2048, 6144, 24);
    // merged rope (q scaled by 1/sqrt(D)) + Vt build (one launch)
    rope_vt<<<dim3(18432), dim3(256), 0, stream>>>(qkv, Vt, 0.08838834764831845f);
    attn_fwd2<<<dim3(512), dim3(256), 0, stream>>>(qkv, Vt);
    gemm_bt<true><<<dim3(16, 32), dim3(256), 0, stream>>>(
        qkv, woutT, out, 2048, 6144, 2048, 2048);
  } else {
    gemm_mixed<true, true, false><<<dim3(96, 64), dim3(256), 0, stream>>>(
        x, wqkv, qkv, 4096, 6144, 2048, 2048, 6144, 6144);
    rope_inplace<<<dim3(16384), dim3(256), 0, stream>>>(qkv, 1.0f);
    attn_fwd<<<dim3(512), dim3(256), 0, stream>>>(qkv);
    gemm_mixed<false, true, true><<<dim3(32, 64), dim3(256), 0, stream>>>(
        qkv, wout, out, 4096, 2048, 2048, 6144, 2048, 2048);
  }
}

// Round 8
// 420.607 us; speedup vs baseline: 1.1383x; 1.1383x over previous
//
#include <hip/hip_runtime.h>
#include <hip/hip_bf16.h>
#include <type_traits>
#include <utility>

typedef unsigned short u16;
typedef unsigned int u32;

#define B_ 2
#define T_ 2048
#define C_ 2048
#define H_ 16
#define D_ 128
#define LDQKV 6144  // row stride of qkv [B*T, 3C]

typedef float float4v __attribute__((ext_vector_type(4)));
typedef short short8 __attribute__((ext_vector_type(8)));

__device__ inline u16 f2bf(float f) {
  u32 u = __builtin_bit_cast(u32, f);
  u32 r = u + 0x7fffu + ((u >> 16) & 1u);  // RNE
  return (u16)(r >> 16);
}
__device__ inline float bfbits2f(u16 b) {
  return __builtin_bit_cast(float, (u32)b << 16);
}
// pack two floats to bf16 pair (round-half-up; cheap, used for softmax P)
__device__ inline u32 pack2bf(float a, float b) {
  u32 ua = (__builtin_bit_cast(u32, a) + 0x8000u) >> 16;
  u32 ub = (__builtin_bit_cast(u32, b) + 0x8000u) & 0xffff0000u;
  return ua | ub;
}

#if defined(__HIP_DEVICE_COMPILE__)
typedef __bf16 bf16x8 __attribute__((ext_vector_type(8)));

template <typename V, typename = void>
struct mfma_takes_short : std::false_type {};
template <typename V>
struct mfma_takes_short<V, std::void_t<decltype(__builtin_amdgcn_mfma_f32_16x16x32_bf16(
    std::declval<V>(), std::declval<V>(), std::declval<float4v>(), 0, 0, 0))>>
    : std::true_type {};

template <typename SV>
__device__ inline float4v mfma_bf16(SV a, SV b, float4v c) {
  if constexpr (mfma_takes_short<SV>::value) {
    return __builtin_amdgcn_mfma_f32_16x16x32_bf16(a, b, c, 0, 0, 0);
  } else {
    return __builtin_amdgcn_mfma_f32_16x16x32_bf16(
        __builtin_bit_cast(bf16x8, a), __builtin_bit_cast(bf16x8, b), c, 0, 0, 0);
  }
}

// Async global->LDS, 16B/lane. LDS dest = wave-uniform base + lane*16.
__device__ inline void async16(u16* lds, const u16* g) {
  typedef __attribute__((address_space(3))) void lds_void;
  typedef __attribute__((address_space(1))) const void g_void;
  __builtin_amdgcn_global_load_lds((g_void*)g, (lds_void*)lds, 16, 0, 0);
}
#endif

// ---------------- merged pre-cast kernel ----------------
// blocks [0,8192): cast x -> xb (bf16)
// blocks [8192,20480): castT wqkv [2048,6144] -> wqkvT [6144,2048]
// blocks [20480,24576): castT wout [2048,2048] -> woutT [2048,2048]
__global__ __launch_bounds__(256) void prep_all(const float* __restrict__ x,
                                                u16* __restrict__ xb,
                                                const float* __restrict__ wqkv,
                                                u16* __restrict__ wqkvT,
                                                const float* __restrict__ wout,
                                                u16* __restrict__ woutT) {
  __shared__ float tile[32][33];
  const int bid = blockIdx.x;
  const int t = threadIdx.x;
  if (bid < 8192) {
    int i = (bid * 256 + t) * 4;
    float4 v = *(const float4*)(x + i);
    alignas(8) u16 o[4] = {f2bf(v.x), f2bf(v.y), f2bf(v.z), f2bf(v.w)};
    *(uint2*)(xb + i) = *(const uint2*)o;
    return;
  }
  const float* src;
  u16* dst;
  int bx, by, R, Cc;
  if (bid < 20480) {
    int b2 = bid - 8192;
    bx = b2 % 192;
    by = b2 / 192;
    src = wqkv;
    dst = wqkvT;
    R = 2048;
    Cc = 6144;
  } else {
    int b3 = bid - 20480;
    bx = b3 & 63;
    by = b3 >> 6;
    src = wout;
    dst = woutT;
    R = 2048;
    Cc = 2048;
  }
  const int r0 = by * 32, c0 = bx * 32;
  const int lr = t >> 3, lc = (t & 7) * 4;
  float4 v = *(const float4*)(src + (size_t)(r0 + lr) * Cc + c0 + lc);
  tile[lr][lc + 0] = v.x;
  tile[lr][lc + 1] = v.y;
  tile[lr][lc + 2] = v.z;
  tile[lr][lc + 3] = v.w;
  __syncthreads();
  alignas(8) u16 o[4];
#pragma unroll
  for (int j = 0; j < 4; ++j) o[j] = f2bf(tile[lc + j][lr]);
  *(uint2*)(dst + (size_t)(c0 + lr) * R + r0 + lc) = *(const uint2*)o;
}

// ---------------- merged rope + vT kernel ----------------
// blocks [0,16384): in-place RoPE on q,k columns (q scaled by qscale)
// blocks [16384,18432): V columns -> Vt [BH,128,2048] per-head transpose
__global__ __launch_bounds__(256) void rope_vt(u16* __restrict__ qkv,
                                               u16* __restrict__ Vt, float qscale) {
  __shared__ u16 lt[64][72];
  const int tid = threadIdx.x;
  const int bid = blockIdx.x;
  if (bid < 16384) {
    int idx = bid * 256 + tid;
    int d = idx & 63;
    int h = (idx >> 6) & 15;
    int t = (idx >> 10) & 2047;
    int b = idx >> 21;
    size_t row = (size_t)(b * T_ + t) * LDQKV;
    u16* qp = qkv + row + h * 128;
    u16* kp = qkv + row + C_ + h * 128;
    float q1 = bfbits2f(qp[d]);
    float q2 = bfbits2f(qp[d + 64]);
    float k1 = bfbits2f(kp[d]);
    float k2 = bfbits2f(kp[d + 64]);
    float invf = exp2f((float)d * -0.20762050593046012f);
    float fr = (float)t * invf;
    float sn, cs;
    sincosf(fr, &sn, &cs);
    qp[d] = f2bf((q1 * cs - q2 * sn) * qscale);
    qp[d + 64] = f2bf((q2 * cs + q1 * sn) * qscale);
    kp[d] = f2bf(k1 * cs - k2 * sn);
    kp[d + 64] = f2bf(k2 * cs + k1 * sn);
    return;
  }
  int b2 = bid - 16384;
  const int bh = b2 & 31;         // 32
  const int tt = (b2 >> 5) & 31;  // 32 t-tiles of 64
  const int dd = b2 >> 10;        // 2 d-tiles of 64
  const int b = bh >> 4, h = bh & 15;
  const int r = tid >> 2;
  const int c4 = (tid & 3) * 16;
  const u16* src = qkv + ((size_t)(b * T_ + tt * 64 + r)) * LDQKV + 2 * C_ + h * 128 + dd * 64 + c4;
  *(uint4*)&lt[r][c4] = *(const uint4*)src;
  *(uint4*)&lt[r][c4 + 8] = *(const uint4*)(src + 8);
  __syncthreads();
  alignas(16) u16 o[16];
#pragma unroll
  for (int j = 0; j < 16; ++j) o[j] = lt[c4 + j][r];
  u16* dst = Vt + ((size_t)(bh * 128 + dd * 64 + r)) * 2048 + tt * 64 + c4;
  *(uint4*)dst = *(const uint4*)o;
  *(uint4*)(dst + 8) = *(const uint4*)(o + 8);
}

// ---------------- 256x256 8-phase GEMM (T1+T2+T3+T4+T5) ----------------
// A [M,K] bf16 rm, BT [N,K] bf16 rm. M%256==0, N%256==0, K%128==0.
// 512 thr / 8 waves (2M x 4N); per-wave 128x64 out; BK=64, 2 K-tiles/iter.
// LDS 128 KiB: 2 bufs x (A 256x64 + B 256x64). Chunk swizzle: logical 8-elem
// chunk cc of row R stored at chunk cc^(R&7) -> conflict-free ds_read_b128,
// and global_load_lds sources are pre-swizzled to match (rule #21).
// v1 schedule (best measured; staging-traffic bound — see session notes).
template <bool CF32>
__global__ __launch_bounds__(512, 2) void gemm256_bt(const u16* __restrict__ A,
                                                     const u16* __restrict__ BT,
                                                     void* __restrict__ Cp,
                                                     int K, int lda, int ldbt, int ldc,
                                                     int nbx) {
#if defined(__HIP_DEVICE_COMPILE__)
  __shared__ alignas(16) u16 As[2][256 * 64];
  __shared__ alignas(16) u16 Bs[2][256 * 64];
  const int tid = threadIdx.x;
  const int lane = tid & 63;
  const int w = tid >> 6;             // 0..7
  const int wm = w >> 2, wn = w & 3;  // wave tile: rows wm*128, cols wn*64
  const int ml = lane & 15, qd = lane >> 4;
  // XCD-aware bijective swizzle (gridDim.x % 8 == 0 guaranteed by launch)
  const int nwg = gridDim.x;
  const int cpx = nwg >> 3;
  const int swz = (blockIdx.x & 7) * cpx + (blockIdx.x >> 3);
  const int by = swz / nbx, bx = swz - by * nbx;
  const int m0 = by * 256, n0 = bx * 256;
  // staging lane decomposition: each async16 issue covers 8 rows x 128B
  const int rowoff = lane >> 3;                  // row within 8-row group
  const int chunk = ((lane & 7) ^ rowoff) * 8;   // pre-swizzled source chunk (u16)
  // per-wave 8-row-group bases for each half-tile (2 issues/wave/half-tile)
  int rA0[2], rA1[2], rB0[2], rB1[2];
#pragma unroll
  for (int j = 0; j < 2; ++j) {
    int g = w * 2 + j;
    rA0[j] = (g >> 3) * 128 + (g & 7) * 8;       // A rows with bit6==0
    rA1[j] = (g >> 3) * 128 + 64 + (g & 7) * 8;  // A rows with bit6==1
    rB0[j] = (g >> 2) * 64 + (g & 3) * 8;        // B rows with bit5==0
    rB1[j] = (g >> 2) * 64 + 32 + (g & 3) * 8;   // B rows with bit5==1
  }
  const int ntiles = K >> 6;
  const int niter = ntiles >> 1;

#define STG_A(bufi, h, kt)                                                       \
  do {                                                                           \
    async16(&As[bufi][rA##h[0] * 64],                                            \
            A + (size_t)(m0 + rA##h[0] + rowoff) * lda + (kt) * 64 + chunk);     \
    async16(&As[bufi][rA##h[1] * 64],                                            \
            A + (size_t)(m0 + rA##h[1] + rowoff) * lda + (kt) * 64 + chunk);     \
  } while (0)
#define STG_B(bufi, h, kt)                                                       \
  do {                                                                           \
    async16(&Bs[bufi][rB##h[0] * 64],                                            \
            BT + (size_t)(n0 + rB##h[0] + rowoff) * ldbt + (kt) * 64 + chunk);   \
    async16(&Bs[bufi][rB##h[1] * 64],                                            \
            BT + (size_t)(n0 + rB##h[1] + rowoff) * ldbt + (kt) * 64 + chunk);   \
  } while (0)
#define LDA8(bufi, mh)                                                           \
  do {                                                                           \
    _Pragma("unroll") for (int mt_ = 0; mt_ < 4; ++mt_)                          \
    _Pragma("unroll") for (int ks_ = 0; ks_ < 2; ++ks_)                          \
      a[mt_][ks_] = *(const short8*)&As[bufi][                                   \
          (wm * 128 + (mh) * 64 + mt_ * 16 + ml) * 64 +                          \
          (((qd + ks_ * 4) ^ (ml & 7)) * 8)];                                    \
  } while (0)
#define LDB4(bufi, nh)                                                           \
  do {                                                                           \
    _Pragma("unroll") for (int nt_ = 0; nt_ < 2; ++nt_)                          \
    _Pragma("unroll") for (int ks_ = 0; ks_ < 2; ++ks_)                          \
      b[nt_][ks_] = *(const short8*)&Bs[bufi][                                   \
          (wn * 64 + (nh) * 32 + nt_ * 16 + ml) * 64 +                           \
          (((qd + ks_ * 4) ^ (ml & 7)) * 8)];                                    \
  } while (0)
#define MMA16(mh, nh)                                                            \
  do {                                                                           \
    __builtin_amdgcn_s_setprio(1);                                               \
    _Pragma("unroll") for (int ks_ = 0; ks_ < 2; ++ks_)                          \
    _Pragma("unroll") for (int mt_ = 0; mt_ < 4; ++mt_)                          \
    _Pragma("unroll") for (int nt_ = 0; nt_ < 2; ++nt_)                          \
      acc[(mh) * 4 + mt_][(nh) * 2 + nt_] = mfma_bf16(                           \
          a[mt_][ks_], b[nt_][ks_], acc[(mh) * 4 + mt_][(nh) * 2 + nt_]);        \
    __builtin_amdgcn_s_setprio(0);                                               \
  } while (0)
#define BAR __builtin_amdgcn_s_barrier()
#define LGKM0 asm volatile("s_waitcnt lgkmcnt(0)" ::: "memory")
#define LGKM8 asm volatile("s_waitcnt lgkmcnt(8)" ::: "memory")
#define VM4 asm volatile("s_waitcnt vmcnt(4)" ::: "memory")

  float4v acc[8][4] = {};
  short8 a[4][2], b[2][2];

  // prologue: tile0 fully + tile1 front halves; vmcnt(4) = tile0 landed
  STG_A(0, 0, 0);
  STG_B(0, 0, 0);
  STG_A(0, 1, 0);
  STG_B(0, 1, 0);
  STG_A(1, 0, 1);
  STG_B(1, 0, 1);
  VM4;
  BAR;

  for (int i = 0; i < niter; ++i) {
    const int tb = 2 * i + 1;
    // clamp prefetch tiles in last iter: keeps vmcnt accounting uniform;
    // clamped stages write only dead LDS regions.
    const int t2 = (2 * i + 2 < ntiles) ? 2 * i + 2 : ntiles - 1;
    const int t3 = (2 * i + 3 < ntiles) ? 2 * i + 3 : ntiles - 1;
    // ---- P1: quad(0,0) of tile 2i (buf0) ----
    LDA8(0, 0);
    LDB4(0, 0);
    STG_A(1, 1, tb);
    LGKM8;
    BAR; LGKM0; MMA16(0, 0); BAR;
    // ---- P2: quad(0,1) ----
    LDB4(0, 1);
    STG_B(1, 1, tb);
    BAR; LGKM0; MMA16(0, 1); BAR;
    // ---- P3: quad(1,0) ----
    LDA8(0, 1);
    LDB4(0, 0);
    STG_A(0, 0, t2);
    LGKM8;
    BAR; LGKM0; MMA16(1, 0); BAR;
    // ---- P4: quad(1,1); gate tile 2i+1 (covers through P2) ----
    LDB4(0, 1);
    STG_B(0, 0, t2);
    VM4;
    BAR; LGKM0; MMA16(1, 1); BAR;
    // ---- P5: quad(0,0) of tile 2i+1 (buf1) ----
    LDA8(1, 0);
    LDB4(1, 0);
    STG_A(0, 1, t2);
    LGKM8;
    BAR; LGKM0; MMA16(0, 0); BAR;
    // ---- P6: quad(0,1) ----
    LDB4(1, 1);
    STG_B(0, 1, t2);
    BAR; LGKM0; MMA16(0, 1); BAR;
    // ---- P7: quad(1,0) ----
    LDA8(1, 1);
    LDB4(1, 0);
    STG_A(1, 0, t3);
    LGKM8;
    BAR; LGKM0; MMA16(1, 0); BAR;
    // ---- P8: quad(1,1); gate tile 2i+2 (covers through P6) ----
    LDB4(1, 1);
    STG_B(1, 0, t3);
    VM4;
    BAR; LGKM0; MMA16(1, 1); BAR;
  }

#pragma unroll
  for (int mt = 0; mt < 8; ++mt) {
#pragma unroll
    for (int nt = 0; nt < 4; ++nt) {
#pragma unroll
      for (int r = 0; r < 4; ++r) {
        int row = m0 + wm * 128 + mt * 16 + qd * 4 + r;
        int col = n0 + wn * 64 + nt * 16 + ml;
        if constexpr (CF32) {
          ((float*)Cp)[(size_t)row * ldc + col] = acc[mt][nt][r];
        } else {
          ((u16*)Cp)[(size_t)row * ldc + col] = f2bf(acc[mt][nt][r]);
        }
      }
    }
  }
#undef STG_A
#undef STG_B
#undef LDA8
#undef LDB4
#undef MMA16
#undef BAR
#undef LGKM0
#undef LGKM8
#undef VM4
#endif
}

// ---------------- m97-style GEMM (1D grid + XCD swizzle) ----------------
// grid = nwg (must be %8==0); nbx = tiles along N. Each XCD gets a
// contiguous chunk of C row-panels -> better L2 panel reuse (T1).
template <bool CF32>
__global__ __launch_bounds__(256) void gemm_bt(const u16* __restrict__ A,
                                               const u16* __restrict__ BT,
                                               void* __restrict__ Cp,
                                               int K, int lda, int ldbt, int ldc,
                                               int nbx) {
#if defined(__HIP_DEVICE_COMPILE__)
  __shared__ u16 As[4096];  // 128x32 [m][k] linear
  __shared__ u16 Bs[4096];  // 128x32 [n][k] linear
  const int tid = threadIdx.x;
  const int lane = tid & 63;
  const int w = tid >> 6;
  const int wm = w & 1, wn = w >> 1;
  const int ml = lane & 15, qd = lane >> 4;
  const int nwg = gridDim.x;
  const int cpx = nwg >> 3;
  const int swz = (blockIdx.x & 7) * cpx + (blockIdx.x >> 3);
  const int by = swz / nbx, bx = swz - by * nbx;
  const int m0 = by * 128, n0 = bx * 128;
  const int sm = lane >> 2, sk = (lane & 3) * 8;
  const u16* gA[2];
  const u16* gB[2];
  u16 *lA[2], *lB[2];
#pragma unroll
  for (int r = 0; r < 2; ++r) {
    int seg = r * 4 + w;
    gA[r] = A + (size_t)(m0 + seg * 16 + sm) * lda + sk;
    gB[r] = BT + (size_t)(n0 + seg * 16 + sm) * ldbt + sk;
    lA[r] = As + seg * 512;
    lB[r] = Bs + seg * 512;
  }
  float4v acc[4][4] = {};
  for (int kk = 0; kk < K; kk += 32) {
    __syncthreads();
    async16(lA[0], gA[0] + kk);
    async16(lA[1], gA[1] + kk);
    async16(lB[0], gB[0] + kk);
    async16(lB[1], gB[1] + kk);
    __syncthreads();
    short8 a[4], b[4];
#pragma unroll
    for (int mt = 0; mt < 4; ++mt)
      a[mt] = *(const short8*)(As + (wm * 64 + mt * 16 + ml) * 32 + qd * 8);
#pragma unroll
    for (int nt = 0; nt < 4; ++nt)
      b[nt] = *(const short8*)(Bs + (wn * 64 + nt * 16 + ml) * 32 + qd * 8);
#pragma unroll
    for (int mt = 0; mt < 4; ++mt)
#pragma unroll
      for (int nt = 0; nt < 4; ++nt) acc[mt][nt] = mfma_bf16(a[mt], b[nt], acc[mt][nt]);
  }
#pragma unroll
  for (int mt = 0; mt < 4; ++mt) {
#pragma unroll
    for (int nt = 0; nt < 4; ++nt) {
#pragma unroll
      for (int r = 0; r < 4; ++r) {
        int row = m0 + wm * 64 + mt * 16 + qd * 4 + r;
        int col = n0 + wn * 64 + nt * 16 + ml;
        if constexpr (CF32) {
          ((float*)Cp)[(size_t)row * ldc + col] = acc[mt][nt][r];
        } else {
          ((u16*)Cp)[(size_t)row * ldc + col] = f2bf(acc[mt][nt][r]);
        }
      }
    }
  }
#endif
}

// ---------------- fallback GEMM ----------------
template <bool AF32, bool BF32, bool CF32>
__global__ __launch_bounds__(256) void gemm_mixed(const void* __restrict__ Ap,
                                                  const void* __restrict__ Bp,
                                                  void* __restrict__ Cp,
                                                  int M, int N, int K,
                                                  int lda, int ldb, int ldc) {
#if defined(__HIP_DEVICE_COMPILE__)
  __shared__ u16 As[64][40];
  __shared__ u16 Bs[64][40];
  const int tid = threadIdx.x;
  const int lane = tid & 63;
  const int w = tid >> 6;
  const int m0 = blockIdx.y * 64;
  const int n0 = blockIdx.x * 64;
  const int arow = tid >> 2, acol = (tid & 3) * 8;
  const int brow = tid >> 3, bcol = (tid & 7) * 8;
  const int ml = lane & 15, qd = lane >> 4;
  float4v acc[4] = {};
  for (int kk = 0; kk < K; kk += 32) {
    __syncthreads();
    if constexpr (AF32) {
      const float* A = (const float*)Ap;
      const float* src = A + (size_t)(m0 + arow) * lda + (kk + acol);
      float4 f0 = *(const float4*)src;
      float4 f1 = *(const float4*)(src + 4);
      alignas(16) u16 tmp[8] = {f2bf(f0.x), f2bf(f0.y), f2bf(f0.z), f2bf(f0.w),
                                f2bf(f1.x), f2bf(f1.y), f2bf(f1.z), f2bf(f1.w)};
      *(uint4*)(&As[arow][acol]) = *(const uint4*)tmp;
    } else {
      const u16* A = (const u16*)Ap;
      *(uint4*)(&As[arow][acol]) = *(const uint4*)(A + (size_t)(m0 + arow) * lda + (kk + acol));
    }
    if constexpr (BF32) {
      const float* Bm = (const float*)Bp;
      const float* src = Bm + (size_t)(kk + brow) * ldb + (n0 + bcol);
      float4 f0 = *(const float4*)src;
      float4 f1 = *(const float4*)(src + 4);
      float fv[8] = {f0.x, f0.y, f0.z, f0.w, f1.x, f1.y, f1.z, f1.w};
#pragma unroll
      for (int i = 0; i < 8; ++i) Bs[bcol + i][brow] = f2bf(fv[i]);
    } else {
      const u16* Bm = (const u16*)Bp;
      uint4 bv = *(const uint4*)(Bm + (size_t)(kk + brow) * ldb + (n0 + bcol));
      const u16* bsp = (const u16*)&bv;
#pragma unroll
      for (int i = 0; i < 8; ++i) Bs[bcol + i][brow] = bsp[i];
    }
    __syncthreads();
    short8 af = *(const short8*)(&As[w * 16 + ml][qd * 8]);
#pragma unroll
    for (int nt = 0; nt < 4; ++nt) {
      short8 bf = *(const short8*)(&Bs[nt * 16 + ml][qd * 8]);
      acc[nt] = mfma_bf16(af, bf, acc[nt]);
    }
  }
#pragma unroll
  for (int nt = 0; nt < 4; ++nt) {
#pragma unroll
    for (int r = 0; r < 4; ++r) {
      int row = m0 + w * 16 + qd * 4 + r;
      int col = n0 + nt * 16 + ml;
      if constexpr (CF32) {
        ((float*)Cp)[(size_t)row * ldc + col] = acc[nt][r];
      } else {
        ((u16*)Cp)[(size_t)row * ldc + col] = f2bf(acc[nt][r]);
      }
    }
  }
#endif
}

// In-place RoPE on qkv [B,T,3C] bf16; q additionally scaled by qscale.
// (fallback path only; main path uses rope_vt)
__global__ __launch_bounds__(256) void rope_inplace(u16* __restrict__ qkv, float qscale) {
  int idx = blockIdx.x * 256 + threadIdx.x;
  int d = idx & 63;
  int h = (idx >> 6) & 15;
  int t = (idx >> 10) & 2047;
  int b = idx >> 21;
  size_t row = (size_t)(b * T_ + t) * LDQKV;
  u16* qp = qkv + row + h * 128;
  u16* kp = qkv + row + C_ + h * 128;
  float q1 = bfbits2f(qp[d]);
  float q2 = bfbits2f(qp[d + 64]);
  float k1 = bfbits2f(kp[d]);
  float k2 = bfbits2f(kp[d + 64]);
  float invf = exp2f((float)d * -0.20762050593046012f);
  float fr = (float)t * invf;
  float sn, cs;
  sincosf(fr, &sn, &cs);
  qp[d] = f2bf((q1 * cs - q2 * sn) * qscale);
  qp[d + 64] = f2bf((q2 * cs + q1 * sn) * qscale);
  kp[d] = f2bf(k1 * cs - k2 * sn);
  kp[d + 64] = f2bf(k2 * cs + k1 * sn);
}

// MFMA flash attention v3 (best-measured config, round-6: 417.5 us total):
// S^T = K Q^T orientation, double-buffered async K/V staging (stage c+1 while
// computing c; ONE barrier + vmcnt(0) per chunk). Q pre-scaled by 1/sqrt(D).
// Block: 128 q-rows of one (b,h); 4 waves x 32 q-rows. Key chunks of 64.
// LDS = 32K (kS dbuf) + 32K (vS dbuf) + 10K (pS) = 74 KiB -> 2 blocks/CU.
// MEASURED-NEGATIVE variants (do not re-add without within-probe A/B):
//   exp2-domain/defer-max/setprio (-18us, r5); single-buf+bounds(256,3)
//   (VGPR capped 84 -> spills, attn 161us, r7).
__global__ __launch_bounds__(256, 2) void attn_fwd2(u16* __restrict__ qkv,
                                                    const u16* __restrict__ Vt) {
#if defined(__HIP_DEVICE_COMPILE__)
  __shared__ alignas(16) u16 kS[2][64 * 128];  // [key][d], swizzled slots
  __shared__ alignas(16) u16 vS[2][128 * 64];  // [d][key], swizzled slots
  __shared__ alignas(16) u16 pS[4][32][40];    // per-wave P [q][32 keys], +8 pad
  const int tid = threadIdx.x;
  const int lane = tid & 63;
  const int w = tid >> 6;
  const int ml = lane & 15, qd = lane >> 4;
  const int gx = blockIdx.x;
  const int half = gx >> 8, rem = gx & 255;
  const int bh = rem >> 3, q3 = rem & 7;
  const int qt = half ? q3 : (15 - q3);  // pair long+short tiles across halves
  const int b = bh >> 4, h = bh & 15;
  const int hc = h * 128;
  const int m0 = qt * 128;
  const size_t rb = (size_t)(b * T_);
  // Q B-frags in registers for whole block: qf[qtile][k4]; lane n=ml -> q-row
  short8 qf[2][4];
#pragma unroll
  for (int m = 0; m < 2; ++m) {
    const u16* qp = qkv + (rb + m0 + w * 32 + m * 16 + ml) * LDQKV + hc;
#pragma unroll
    for (int k4 = 0; k4 < 4; ++k4) qf[m][k4] = *(const short8*)(qp + k4 * 32 + qd * 8);
  }
  float4v acc[2][8] = {};
  float mi[2] = {-1.0e30f, -1.0e30f}, li[2] = {0.f, 0.f};
  const int nchunk = 2 * qt + 2;
  // staging decode (closed forms)
  const int krow0 = w * 16 + qd;                    // + i*4
  const int vd0 = w * 32 + (lane >> 3);             // + i*8
  const int vsegoff = ((lane & 7) ^ (lane >> 3)) * 8;
  const size_t vtbase = ((size_t)bh * 128) * 2048;

#define STAGE(cc, bi)                                                        \
  do {                                                                       \
    _Pragma("unroll") for (int i_ = 0; i_ < 4; ++i_) {                       \
      int key_ = krow0 + i_ * 4;                                             \
      int seg_ = (ml ^ (i_ * 4 + qd)) * 8;                                   \
      async16(kS[bi] + (w * 4 + i_) * 512,                                   \
              qkv + (rb + (cc) * 64 + key_) * LDQKV + C_ + hc + seg_);       \
    }                                                                        \
    _Pragma("unroll") for (int i_ = 0; i_ < 4; ++i_) {                       \
      int d_ = vd0 + i_ * 8;                                                 \
      async16(vS[bi] + (w * 4 + i_) * 512,                                   \
              Vt + vtbase + (size_t)d_ * 2048 + (cc) * 64 + vsegoff);        \
    }                                                                        \
  } while (0)

  // prologue: chunk 0 -> buf0
  STAGE(0, 0);
  asm volatile("s_waitcnt vmcnt(0)" ::: "memory");
  __syncthreads();

  for (int c = 0; c < nchunk; ++c) {
    const int cur = c & 1;
    // prefetch next chunk into the other buffer (its last readers finished
    // before the barrier that ended iteration c-1).
    if (c + 1 < nchunk) STAGE(c + 1, cur ^ 1);
    if (c * 64 <= m0 + w * 32 + 31) {  // skip if all keys future for this wave
      const u16* kb = kS[cur];
      const u16* vb = vS[cur];
      // ---- S^T = K Q^T : s[kt][qtile], C row=key(qd*4+r), col=q(ml) ----
      float4v s[4][2] = {};
#pragma unroll
      for (int kt = 0; kt < 4; ++kt) {
#pragma unroll
        for (int k4 = 0; k4 < 4; ++k4) {
          short8 kf = *(const short8*)(kb + ((kt * 16 + ml) * 16 + ((k4 * 4 + qd) ^ ml)) * 8);
          s[kt][0] = mfma_bf16(kf, qf[0][k4], s[kt][0]);
          s[kt][1] = mfma_bf16(kf, qf[1][k4], s[kt][1]);
        }
      }
      const bool domask = (c * 64 + 63) > (m0 + w * 32);
      float alpha[2];
#pragma unroll
      for (int m = 0; m < 2; ++m) {
        int qrow = m0 + w * 32 + m * 16 + ml;
        if (domask) {
#pragma unroll
          for (int kt = 0; kt < 4; ++kt)
#pragma unroll
            for (int r = 0; r < 4; ++r) {
              int key = c * 64 + kt * 16 + qd * 4 + r;
              if (key > qrow) s[kt][m][r] = -1.0e30f;
            }
        }
        float mx = -1.0e30f;
#pragma unroll
        for (int kt = 0; kt < 4; ++kt)
#pragma unroll
          for (int r = 0; r < 4; ++r) mx = fmaxf(mx, s[kt][m][r]);
        mx = fmaxf(mx, __shfl_xor(mx, 16, 64));
        mx = fmaxf(mx, __shfl_xor(mx, 32, 64));
        float mnew = fmaxf(mi[m], mx);
        float a = __expf(mi[m] - mnew);
        float sm = 0.f;
#pragma unroll
        for (int kt = 0; kt < 4; ++kt)
#pragma unroll
          for (int r = 0; r < 4; ++r) {
            float p = __expf(s[kt][m][r] - mnew);
            s[kt][m][r] = p;
            sm += p;
          }
        sm += __shfl_xor(sm, 16, 64);
        sm += __shfl_xor(sm, 32, 64);
        li[m] = li[m] * a + sm;
        mi[m] = mnew;
        alpha[m] = a;
      }
      // rescale O (alpha lives at lane ml=q'; broadcast to rows qd*4+r)
#pragma unroll
      for (int m = 0; m < 2; ++m) {
#pragma unroll
        for (int r = 0; r < 4; ++r) {
          float aq = __shfl(alpha[m], qd * 4 + r, 64);
#pragma unroll
          for (int dt = 0; dt < 8; ++dt) acc[m][dt][r] *= aq;
        }
      }
      // ---- O += P V, in two 32-key halves through the small pS buffer ----
#pragma unroll
      for (int k2 = 0; k2 < 2; ++k2) {
#pragma unroll
        for (int m = 0; m < 2; ++m) {
#pragma unroll
          for (int ktl = 0; ktl < 2; ++ktl) {
            int kt = k2 * 2 + ktl;
            uint2 pk;
            pk.x = pack2bf(s[kt][m][0], s[kt][m][1]);
            pk.y = pack2bf(s[kt][m][2], s[kt][m][3]);
            *(uint2*)&pS[w][m * 16 + ml][ktl * 16 + qd * 4] = pk;
          }
        }
        short8 pa0 = *(const short8*)&pS[w][ml][qd * 8];
        short8 pa1 = *(const short8*)&pS[w][16 + ml][qd * 8];
#pragma unroll
        for (int dt = 0; dt < 8; ++dt) {
          int d = dt * 16 + ml;
          short8 vf = *(const short8*)(vb + (d * 8 + ((k2 * 4 + qd) ^ (ml & 7))) * 8);
          acc[0][dt] = mfma_bf16(pa0, vf, acc[0][dt]);
          acc[1][dt] = mfma_bf16(pa1, vf, acc[1][dt]);
        }
      }
    }
    // drain own prefetch loads (issued a full compute-phase ago), then
    // barrier: next iteration may read buf[cur^1] / overwrite buf[cur].
    asm volatile("s_waitcnt vmcnt(0)" ::: "memory");
    __syncthreads();
  }
#undef STAGE
  // ---- epilogue: O/l -> Q cols of qkv ----
#pragma unroll
  for (int m = 0; m < 2; ++m) {
#pragma unroll
    for (int r = 0; r < 4; ++r) {
      float inv = 1.0f / __shfl(li[m], qd * 4 + r, 64);
      size_t row = rb + m0 + w * 32 + m * 16 + qd * 4 + r;
#pragma unroll
      for (int dt = 0; dt < 8; ++dt)
        qkv[row * LDQKV + hc + dt * 16 + ml] = f2bf(acc[m][dt][r] * inv);
    }
  }
#endif
}

// Old flash attention (fallback path; expects unscaled Q).
__global__ __launch_bounds__(256, 2) void attn_fwd(u16* __restrict__ qkv) {
#if defined(__HIP_DEVICE_COMPILE__)
  __shared__ alignas(16) u16 ks[64][136];
  __shared__ alignas(16) u16 vt[128][72];
  __shared__ alignas(16) u16 pb[4][32][72];
  const int tid = threadIdx.x;
  const int lane = tid & 63;
  const int w = tid >> 6;
  const int ml = lane & 15, qd = lane >> 4;
  const int gx = blockIdx.x;
  const int half = gx >> 8;
  const int rem = gx & 255;
  const int bh = rem >> 3;
  const int q3 = rem & 7;
  const int qt = half ? q3 : (15 - q3);
  const int b = bh >> 4, h = bh & 15;
  const int hc = h * 128;
  const int m0 = qt * 128;
  const size_t rb = (size_t)(b * T_);
  short8 qf[2][4];
#pragma unroll
  for (int m = 0; m < 2; ++m) {
    const u16* qp = qkv + (rb + m0 + w * 32 + m * 16 + ml) * LDQKV + hc;
#pragma unroll
    for (int k4 = 0; k4 < 4; ++k4) qf[m][k4] = *(const short8*)(qp + k4 * 32 + qd * 8);
  }
  float4v acc[2][8] = {};
  float mi[2][4], li[2][4];
#pragma unroll
  for (int m = 0; m < 2; ++m)
#pragma unroll
    for (int r = 0; r < 4; ++r) { mi[m][r] = -1.0e30f; li[m][r] = 0.f; }
  const float scale = 0.08838834764831845f;
  const int srow = tid >> 2;
  const int scol = (tid & 3) * 32;
  const int nchunk = 2 * qt + 2;
  for (int c = 0; c < nchunk; ++c) {
    __syncthreads();
    {
      const u16* kp = qkv + (rb + c * 64 + srow) * LDQKV + C_ + hc + scol;
      const u16* vp = qkv + (rb + c * 64 + srow) * LDQKV + 2 * C_ + hc + scol;
#pragma unroll
      for (int i = 0; i < 4; ++i)
        *(uint4*)&ks[srow][scol + i * 8] = *(const uint4*)(kp + i * 8);
#pragma unroll
      for (int i = 0; i < 4; ++i) {
        uint4 vv = *(const uint4*)(vp + i * 8);
        const u16* e = (const u16*)&vv;
#pragma unroll
        for (int t = 0; t < 8; ++t) vt[scol + i * 8 + t][srow] = e[t];
      }
    }
    __syncthreads();
    if (c * 64 > m0 + w * 32 + 31) continue;
    float4v s[2][4] = {};
#pragma unroll
    for (int t = 0; t < 4; ++t) {
#pragma unroll
      for (int k4 = 0; k4 < 4; ++k4) {
        short8 bf = *(const short8*)(&ks[t * 16 + ml][k4 * 32 + qd * 8]);
        s[0][t] = mfma_bf16(qf[0][k4], bf, s[0][t]);
        s[1][t] = mfma_bf16(qf[1][k4], bf, s[1][t]);
      }
    }
    const bool domask = (c * 64 + 63) > (m0 + w * 32);
#pragma unroll
    for (int m = 0; m < 2; ++m) {
      float al[4];
#pragma unroll
      for (int r = 0; r < 4; ++r) {
        float x0 = s[m][0][r] * scale;
        float x1 = s[m][1][r] * scale;
        float x2 = s[m][2][r] * scale;
        float x3 = s[m][3][r] * scale;
        if (domask) {
          int row = m0 + w * 32 + m * 16 + qd * 4 + r;
          int j0 = c * 64 + ml;
          if (j0 > row) x0 = -1.0e30f;
          if (j0 + 16 > row) x1 = -1.0e30f;
          if (j0 + 32 > row) x2 = -1.0e30f;
          if (j0 + 48 > row) x3 = -1.0e30f;
        }
        float mx = fmaxf(fmaxf(x0, x1), fmaxf(x2, x3));
        mx = fmaxf(mx, __shfl_xor(mx, 1));
        mx = fmaxf(mx, __shfl_xor(mx, 2));
        mx = fmaxf(mx, __shfl_xor(mx, 4));
        mx = fmaxf(mx, __shfl_xor(mx, 8));
        float mnew = fmaxf(mi[m][r], mx);
        float a = __expf(mi[m][r] - mnew);
        float p0 = __expf(x0 - mnew);
        float p1 = __expf(x1 - mnew);
        float p2 = __expf(x2 - mnew);
        float p3 = __expf(x3 - mnew);
        float sm = p0 + p1 + p2 + p3;
        sm += __shfl_xor(sm, 1);
        sm += __shfl_xor(sm, 2);
        sm += __shfl_xor(sm, 4);
        sm += __shfl_xor(sm, 8);
        li[m][r] = li[m][r] * a + sm;
        mi[m][r] = mnew;
        al[r] = a;
        int prow = m * 16 + qd * 4 + r;
        pb[w][prow][ml] = f2bf(p0);
        pb[w][prow][16 + ml] = f2bf(p1);
        pb[w][prow][32 + ml] = f2bf(p2);
        pb[w][prow][48 + ml] = f2bf(p3);
      }
#pragma unroll
      for (int d = 0; d < 8; ++d) {
        acc[m][d][0] *= al[0];
        acc[m][d][1] *= al[1];
        acc[m][d][2] *= al[2];
        acc[m][d][3] *= al[3];
      }
    }
#pragma unroll
    for (int k2 = 0; k2 < 2; ++k2) {
      short8 pa0 = *(const short8*)(&pb[w][ml][k2 * 32 + qd * 8]);
      short8 pa1 = *(const short8*)(&pb[w][16 + ml][k2 * 32 + qd * 8]);
#pragma unroll
      for (int d = 0; d < 8; ++d) {
        short8 vf = *(const short8*)(&vt[d * 16 + ml][k2 * 32 + qd * 8]);
        acc[0][d] = mfma_bf16(pa0, vf, acc[0][d]);
        acc[1][d] = mfma_bf16(pa1, vf, acc[1][d]);
      }
    }
  }
#pragma unroll
  for (int m = 0; m < 2; ++m) {
#pragma unroll
    for (int r = 0; r < 4; ++r) {
      float inv = 1.0f / li[m][r];
      size_t row = rb + m0 + w * 32 + m * 16 + qd * 4 + r;
#pragma unroll
      for (int d = 0; d < 8; ++d)
        qkv[row * LDQKV + hc + d * 16 + ml] = f2bf(acc[m][d][r] * inv);
    }
  }
#endif
}

extern "C" void kernel_launch(void* const* d_in, const int* in_sizes, int n_in,
                              void* d_out, int out_size, void* d_ws, size_t ws_size,
                              hipStream_t stream) {
  const float* x = (const float*)d_in[0];     // [B,T,C] fp32
  const float* wqkv = (const float*)d_in[1];  // [C,3C] fp32
  const float* wout = (const float*)d_in[2];  // [C,C] fp32
  float* out = (float*)d_out;                 // [B,T,C] fp32
  char* ws = (char*)d_ws;
  u16* qkv = (u16*)ws;  // [4096, 6144] bf16 = 48 MB; Q cols reused as Y

  const size_t MB = 1024 * 1024;
  if (ws_size >= 96 * MB) {
    u16* xb = (u16*)(ws + 48 * MB);     // [4096,2048] bf16, 16 MB
    u16* wqkvT = (u16*)(ws + 64 * MB);  // [6144,2048] bf16, 24 MB
    u16* Vt = (u16*)(ws + 64 * MB);     // [32,128,2048] bf16, 16 MB (reuses wqkvT after GEMM1)
    u16* woutT = (u16*)(ws + 88 * MB);  // [2048,2048] bf16, 8 MB
    // merged pre-casts: x->xb, wqkv->wqkvT, wout->woutT (one launch)
    prep_all<<<dim3(24576), dim3(256), 0, stream>>>(x, xb, wqkv, wqkvT, wout, woutT);
    // GEMM1: 256x256 8-phase pipeline; grid = (4096/256)*(6144/256) = 384 (%8==0)
    gemm256_bt<false><<<dim3(384), dim3(512), 0, stream>>>(
        xb, wqkvT, qkv, 2048, 2048, 2048, 6144, 24);
    // merged rope (q scaled by 1/sqrt(D)) + Vt build (one launch)
    rope_vt<<<dim3(18432), dim3(256), 0, stream>>>(qkv, Vt, 0.08838834764831845f);
    attn_fwd2<<<dim3(512), dim3(256), 0, stream>>>(qkv, Vt);
    // GEMM2: 1D grid 512 (= 32 row-tiles x 16 col-tiles), XCD-swizzled
    gemm_bt<true><<<dim3(512), dim3(256), 0, stream>>>(
        qkv, woutT, out, 2048, 6144, 2048, 2048, 16);
  } else {
    gemm_mixed<true, true, false><<<dim3(96, 64), dim3(256), 0, stream>>>(
        x, wqkv, qkv, 4096, 6144, 2048, 2048, 6144, 6144);
    rope_inplace<<<dim3(16384), dim3(256), 0, stream>>>(qkv, 1.0f);
    attn_fwd<<<dim3(512), dim3(256), 0, stream>>>(qkv);
    gemm_mixed<false, true, true><<<dim3(32, 64), dim3(256), 0, stream>>>(
        qkv, wout, out, 4096, 2048, 2048, 6144, 2048, 2048);
  }
}

// Round 10
// 416.395 us; speedup vs baseline: 1.1498x; 1.0101x over previous
//
#include <hip/hip_runtime.h>
#include <hip/hip_bf16.h>
#include <type_traits>
#include <utility>

typedef unsigned short u16;
typedef unsigned int u32;

#define B_ 2
#define T_ 2048
#define C_ 2048
#define H_ 16
#define D_ 128
#define LDQKV 6144  // row stride of qkv [B*T, 3C]

typedef float float4v __attribute__((ext_vector_type(4)));
typedef short short8 __attribute__((ext_vector_type(8)));

__device__ inline u16 f2bf(float f) {
  u32 u = __builtin_bit_cast(u32, f);
  u32 r = u + 0x7fffu + ((u >> 16) & 1u);  // RNE
  return (u16)(r >> 16);
}
__device__ inline float bfbits2f(u16 b) {
  return __builtin_bit_cast(float, (u32)b << 16);
}
// pack two floats to bf16 pair (round-half-up; cheap, used for softmax P)
__device__ inline u32 pack2bf(float a, float b) {
  u32 ua = (__builtin_bit_cast(u32, a) + 0x8000u) >> 16;
  u32 ub = (__builtin_bit_cast(u32, b) + 0x8000u) & 0xffff0000u;
  return ua | ub;
}

#if defined(__HIP_DEVICE_COMPILE__)
typedef __bf16 bf16x8 __attribute__((ext_vector_type(8)));

template <typename V, typename = void>
struct mfma_takes_short : std::false_type {};
template <typename V>
struct mfma_takes_short<V, std::void_t<decltype(__builtin_amdgcn_mfma_f32_16x16x32_bf16(
    std::declval<V>(), std::declval<V>(), std::declval<float4v>(), 0, 0, 0))>>
    : std::true_type {};

template <typename SV>
__device__ inline float4v mfma_bf16(SV a, SV b, float4v c) {
  if constexpr (mfma_takes_short<SV>::value) {
    return __builtin_amdgcn_mfma_f32_16x16x32_bf16(a, b, c, 0, 0, 0);
  } else {
    return __builtin_amdgcn_mfma_f32_16x16x32_bf16(
        __builtin_bit_cast(bf16x8, a), __builtin_bit_cast(bf16x8, b), c, 0, 0, 0);
  }
}

// Async global->LDS, 16B/lane. LDS dest = wave-uniform base + lane*16.
__device__ inline void async16(u16* lds, const u16* g) {
  typedef __attribute__((address_space(3))) void lds_void;
  typedef __attribute__((address_space(1))) const void g_void;
  __builtin_amdgcn_global_load_lds((g_void*)g, (lds_void*)lds, 16, 0, 0);
}
#endif

// ---------------- merged pre-cast kernel ----------------
// blocks [0,8192): cast x -> xb (bf16)
// blocks [8192,20480): castT wqkv [2048,6144] -> wqkvT [6144,2048]
// blocks [20480,24576): castT wout [2048,2048] -> woutT [2048,2048]
__global__ __launch_bounds__(256) void prep_all(const float* __restrict__ x,
                                                u16* __restrict__ xb,
                                                const float* __restrict__ wqkv,
                                                u16* __restrict__ wqkvT,
                                                const float* __restrict__ wout,
                                                u16* __restrict__ woutT) {
  __shared__ float tile[32][33];
  const int bid = blockIdx.x;
  const int t = threadIdx.x;
  if (bid < 8192) {
    int i = (bid * 256 + t) * 4;
    float4 v = *(const float4*)(x + i);
    alignas(8) u16 o[4] = {f2bf(v.x), f2bf(v.y), f2bf(v.z), f2bf(v.w)};
    *(uint2*)(xb + i) = *(const uint2*)o;
    return;
  }
  const float* src;
  u16* dst;
  int bx, by, R, Cc;
  if (bid < 20480) {
    int b2 = bid - 8192;
    bx = b2 % 192;
    by = b2 / 192;
    src = wqkv;
    dst = wqkvT;
    R = 2048;
    Cc = 6144;
  } else {
    int b3 = bid - 20480;
    bx = b3 & 63;
    by = b3 >> 6;
    src = wout;
    dst = woutT;
    R = 2048;
    Cc = 2048;
  }
  const int r0 = by * 32, c0 = bx * 32;
  const int lr = t >> 3, lc = (t & 7) * 4;
  float4 v = *(const float4*)(src + (size_t)(r0 + lr) * Cc + c0 + lc);
  tile[lr][lc + 0] = v.x;
  tile[lr][lc + 1] = v.y;
  tile[lr][lc + 2] = v.z;
  tile[lr][lc + 3] = v.w;
  __syncthreads();
  alignas(8) u16 o[4];
#pragma unroll
  for (int j = 0; j < 4; ++j) o[j] = f2bf(tile[lc + j][lr]);
  *(uint2*)(dst + (size_t)(c0 + lr) * R + r0 + lc) = *(const uint2*)o;
}

// ---------------- merged rope + vT kernel ----------------
// blocks [0,16384): in-place RoPE on q,k columns (q scaled by qscale)
// blocks [16384,18432): V columns -> Vt [BH,128,2048] per-head transpose
__global__ __launch_bounds__(256) void rope_vt(u16* __restrict__ qkv,
                                               u16* __restrict__ Vt, float qscale) {
  __shared__ u16 lt[64][72];
  const int tid = threadIdx.x;
  const int bid = blockIdx.x;
  if (bid < 16384) {
    int idx = bid * 256 + tid;
    int d = idx & 63;
    int h = (idx >> 6) & 15;
    int t = (idx >> 10) & 2047;
    int b = idx >> 21;
    size_t row = (size_t)(b * T_ + t) * LDQKV;
    u16* qp = qkv + row + h * 128;
    u16* kp = qkv + row + C_ + h * 128;
    float q1 = bfbits2f(qp[d]);
    float q2 = bfbits2f(qp[d + 64]);
    float k1 = bfbits2f(kp[d]);
    float k2 = bfbits2f(kp[d + 64]);
    float invf = exp2f((float)d * -0.20762050593046012f);
    float fr = (float)t * invf;
    float sn, cs;
    sincosf(fr, &sn, &cs);
    qp[d] = f2bf((q1 * cs - q2 * sn) * qscale);
    qp[d + 64] = f2bf((q2 * cs + q1 * sn) * qscale);
    kp[d] = f2bf(k1 * cs - k2 * sn);
    kp[d + 64] = f2bf(k2 * cs + k1 * sn);
    return;
  }
  int b2 = bid - 16384;
  const int bh = b2 & 31;         // 32
  const int tt = (b2 >> 5) & 31;  // 32 t-tiles of 64
  const int dd = b2 >> 10;        // 2 d-tiles of 64
  const int b = bh >> 4, h = bh & 15;
  const int r = tid >> 2;
  const int c4 = (tid & 3) * 16;
  const u16* src = qkv + ((size_t)(b * T_ + tt * 64 + r)) * LDQKV + 2 * C_ + h * 128 + dd * 64 + c4;
  *(uint4*)&lt[r][c4] = *(const uint4*)src;
  *(uint4*)&lt[r][c4 + 8] = *(const uint4*)(src + 8);
  __syncthreads();
  alignas(16) u16 o[16];
#pragma unroll
  for (int j = 0; j < 16; ++j) o[j] = lt[c4 + j][r];
  u16* dst = Vt + ((size_t)(bh * 128 + dd * 64 + r)) * 2048 + tt * 64 + c4;
  *(uint4*)dst = *(const uint4*)o;
  *(uint4*)(dst + 8) = *(const uint4*)(o + 8);
}

// ---------------- 256x256 8-phase GEMM (T1+T2+T3+T4+T5) ----------------
// A [M,K] bf16 rm, BT [N,K] bf16 rm. M%256==0, N%256==0, K%128==0.
// 512 thr / 8 waves (2M x 4N); per-wave 128x64 out; BK=64, 2 K-tiles/iter.
// LDS 128 KiB: 2 bufs x (A 256x64 + B 256x64). Chunk swizzle: logical 8-elem
// chunk cc of row R stored at chunk cc^(R&7) -> conflict-free ds_read_b128,
// and global_load_lds sources are pre-swizzled to match (rule #21).
// v1 schedule (best measured; staging-traffic bound — see session notes).
template <bool CF32>
__global__ __launch_bounds__(512, 2) void gemm256_bt(const u16* __restrict__ A,
                                                     const u16* __restrict__ BT,
                                                     void* __restrict__ Cp,
                                                     int K, int lda, int ldbt, int ldc,
                                                     int nbx) {
#if defined(__HIP_DEVICE_COMPILE__)
  __shared__ alignas(16) u16 As[2][256 * 64];
  __shared__ alignas(16) u16 Bs[2][256 * 64];
  const int tid = threadIdx.x;
  const int lane = tid & 63;
  const int w = tid >> 6;             // 0..7
  const int wm = w >> 2, wn = w & 3;  // wave tile: rows wm*128, cols wn*64
  const int ml = lane & 15, qd = lane >> 4;
  // XCD-aware bijective swizzle (gridDim.x % 8 == 0 guaranteed by launch)
  const int nwg = gridDim.x;
  const int cpx = nwg >> 3;
  const int swz = (blockIdx.x & 7) * cpx + (blockIdx.x >> 3);
  const int by = swz / nbx, bx = swz - by * nbx;
  const int m0 = by * 256, n0 = bx * 256;
  // staging lane decomposition: each async16 issue covers 8 rows x 128B
  const int rowoff = lane >> 3;                  // row within 8-row group
  const int chunk = ((lane & 7) ^ rowoff) * 8;   // pre-swizzled source chunk (u16)
  // per-wave 8-row-group bases for each half-tile (2 issues/wave/half-tile)
  int rA0[2], rA1[2], rB0[2], rB1[2];
#pragma unroll
  for (int j = 0; j < 2; ++j) {
    int g = w * 2 + j;
    rA0[j] = (g >> 3) * 128 + (g & 7) * 8;       // A rows with bit6==0
    rA1[j] = (g >> 3) * 128 + 64 + (g & 7) * 8;  // A rows with bit6==1
    rB0[j] = (g >> 2) * 64 + (g & 3) * 8;        // B rows with bit5==0
    rB1[j] = (g >> 2) * 64 + 32 + (g & 3) * 8;   // B rows with bit5==1
  }
  const int ntiles = K >> 6;
  const int niter = ntiles >> 1;

#define STG_A(bufi, h, kt)                                                       \
  do {                                                                           \
    async16(&As[bufi][rA##h[0] * 64],                                            \
            A + (size_t)(m0 + rA##h[0] + rowoff) * lda + (kt) * 64 + chunk);     \
    async16(&As[bufi][rA##h[1] * 64],                                            \
            A + (size_t)(m0 + rA##h[1] + rowoff) * lda + (kt) * 64 + chunk);     \
  } while (0)
#define STG_B(bufi, h, kt)                                                       \
  do {                                                                           \
    async16(&Bs[bufi][rB##h[0] * 64],                                            \
            BT + (size_t)(n0 + rB##h[0] + rowoff) * ldbt + (kt) * 64 + chunk);   \
    async16(&Bs[bufi][rB##h[1] * 64],                                            \
            BT + (size_t)(n0 + rB##h[1] + rowoff) * ldbt + (kt) * 64 + chunk);   \
  } while (0)
#define LDA8(bufi, mh)                                                           \
  do {                                                                           \
    _Pragma("unroll") for (int mt_ = 0; mt_ < 4; ++mt_)                          \
    _Pragma("unroll") for (int ks_ = 0; ks_ < 2; ++ks_)                          \
      a[mt_][ks_] = *(const short8*)&As[bufi][                                   \
          (wm * 128 + (mh) * 64 + mt_ * 16 + ml) * 64 +                          \
          (((qd + ks_ * 4) ^ (ml & 7)) * 8)];                                    \
  } while (0)
#define LDB4(bufi, nh)                                                           \
  do {                                                                           \
    _Pragma("unroll") for (int nt_ = 0; nt_ < 2; ++nt_)                          \
    _Pragma("unroll") for (int ks_ = 0; ks_ < 2; ++ks_)                          \
      b[nt_][ks_] = *(const short8*)&Bs[bufi][                                   \
          (wn * 64 + (nh) * 32 + nt_ * 16 + ml) * 64 +                           \
          (((qd + ks_ * 4) ^ (ml & 7)) * 8)];                                    \
  } while (0)
#define MMA16(mh, nh)                                                            \
  do {                                                                           \
    __builtin_amdgcn_s_setprio(1);                                               \
    _Pragma("unroll") for (int ks_ = 0; ks_ < 2; ++ks_)                          \
    _Pragma("unroll") for (int mt_ = 0; mt_ < 4; ++mt_)                          \
    _Pragma("unroll") for (int nt_ = 0; nt_ < 2; ++nt_)                          \
      acc[(mh) * 4 + mt_][(nh) * 2 + nt_] = mfma_bf16(                           \
          a[mt_][ks_], b[nt_][ks_], acc[(mh) * 4 + mt_][(nh) * 2 + nt_]);        \
    __builtin_amdgcn_s_setprio(0);                                               \
  } while (0)
#define BAR __builtin_amdgcn_s_barrier()
#define LGKM0 asm volatile("s_waitcnt lgkmcnt(0)" ::: "memory")
#define LGKM8 asm volatile("s_waitcnt lgkmcnt(8)" ::: "memory")
#define VM4 asm volatile("s_waitcnt vmcnt(4)" ::: "memory")

  float4v acc[8][4] = {};
  short8 a[4][2], b[2][2];

  // prologue: tile0 fully + tile1 front halves; vmcnt(4) = tile0 landed
  STG_A(0, 0, 0);
  STG_B(0, 0, 0);
  STG_A(0, 1, 0);
  STG_B(0, 1, 0);
  STG_A(1, 0, 1);
  STG_B(1, 0, 1);
  VM4;
  BAR;

  for (int i = 0; i < niter; ++i) {
    const int tb = 2 * i + 1;
    // clamp prefetch tiles in last iter: keeps vmcnt accounting uniform;
    // clamped stages write only dead LDS regions.
    const int t2 = (2 * i + 2 < ntiles) ? 2 * i + 2 : ntiles - 1;
    const int t3 = (2 * i + 3 < ntiles) ? 2 * i + 3 : ntiles - 1;
    // ---- P1: quad(0,0) of tile 2i (buf0) ----
    LDA8(0, 0);
    LDB4(0, 0);
    STG_A(1, 1, tb);
    LGKM8;
    BAR; LGKM0; MMA16(0, 0); BAR;
    // ---- P2: quad(0,1) ----
    LDB4(0, 1);
    STG_B(1, 1, tb);
    BAR; LGKM0; MMA16(0, 1); BAR;
    // ---- P3: quad(1,0) ----
    LDA8(0, 1);
    LDB4(0, 0);
    STG_A(0, 0, t2);
    LGKM8;
    BAR; LGKM0; MMA16(1, 0); BAR;
    // ---- P4: quad(1,1); gate tile 2i+1 (covers through P2) ----
    LDB4(0, 1);
    STG_B(0, 0, t2);
    VM4;
    BAR; LGKM0; MMA16(1, 1); BAR;
    // ---- P5: quad(0,0) of tile 2i+1 (buf1) ----
    LDA8(1, 0);
    LDB4(1, 0);
    STG_A(0, 1, t2);
    LGKM8;
    BAR; LGKM0; MMA16(0, 0); BAR;
    // ---- P6: quad(0,1) ----
    LDB4(1, 1);
    STG_B(0, 1, t2);
    BAR; LGKM0; MMA16(0, 1); BAR;
    // ---- P7: quad(1,0) ----
    LDA8(1, 1);
    LDB4(1, 0);
    STG_A(1, 0, t3);
    LGKM8;
    BAR; LGKM0; MMA16(1, 0); BAR;
    // ---- P8: quad(1,1); gate tile 2i+2 (covers through P6) ----
    LDB4(1, 1);
    STG_B(1, 0, t3);
    VM4;
    BAR; LGKM0; MMA16(1, 1); BAR;
  }

#pragma unroll
  for (int mt = 0; mt < 8; ++mt) {
#pragma unroll
    for (int nt = 0; nt < 4; ++nt) {
#pragma unroll
      for (int r = 0; r < 4; ++r) {
        int row = m0 + wm * 128 + mt * 16 + qd * 4 + r;
        int col = n0 + wn * 64 + nt * 16 + ml;
        if constexpr (CF32) {
          ((float*)Cp)[(size_t)row * ldc + col] = acc[mt][nt][r];
        } else {
          ((u16*)Cp)[(size_t)row * ldc + col] = f2bf(acc[mt][nt][r]);
        }
      }
    }
  }
#undef STG_A
#undef STG_B
#undef LDA8
#undef LDB4
#undef MMA16
#undef BAR
#undef LGKM0
#undef LGKM8
#undef VM4
#endif
}

// ---------------- m97-style GEMM (1D grid + XCD swizzle) ----------------
// grid = nwg (must be %8==0); nbx = tiles along N. Each XCD gets a
// contiguous chunk of C row-panels -> better L2 panel reuse (T1).
template <bool CF32>
__global__ __launch_bounds__(256) void gemm_bt(const u16* __restrict__ A,
                                               const u16* __restrict__ BT,
                                               void* __restrict__ Cp,
                                               int K, int lda, int ldbt, int ldc,
                                               int nbx) {
#if defined(__HIP_DEVICE_COMPILE__)
  __shared__ u16 As[4096];  // 128x32 [m][k] linear
  __shared__ u16 Bs[4096];  // 128x32 [n][k] linear
  const int tid = threadIdx.x;
  const int lane = tid & 63;
  const int w = tid >> 6;
  const int wm = w & 1, wn = w >> 1;
  const int ml = lane & 15, qd = lane >> 4;
  const int nwg = gridDim.x;
  const int cpx = nwg >> 3;
  const int swz = (blockIdx.x & 7) * cpx + (blockIdx.x >> 3);
  const int by = swz / nbx, bx = swz - by * nbx;
  const int m0 = by * 128, n0 = bx * 128;
  const int sm = lane >> 2, sk = (lane & 3) * 8;
  const u16* gA[2];
  const u16* gB[2];
  u16 *lA[2], *lB[2];
#pragma unroll
  for (int r = 0; r < 2; ++r) {
    int seg = r * 4 + w;
    gA[r] = A + (size_t)(m0 + seg * 16 + sm) * lda + sk;
    gB[r] = BT + (size_t)(n0 + seg * 16 + sm) * ldbt + sk;
    lA[r] = As + seg * 512;
    lB[r] = Bs + seg * 512;
  }
  float4v acc[4][4] = {};
  for (int kk = 0; kk < K; kk += 32) {
    __syncthreads();
    async16(lA[0], gA[0] + kk);
    async16(lA[1], gA[1] + kk);
    async16(lB[0], gB[0] + kk);
    async16(lB[1], gB[1] + kk);
    __syncthreads();
    short8 a[4], b[4];
#pragma unroll
    for (int mt = 0; mt < 4; ++mt)
      a[mt] = *(const short8*)(As + (wm * 64 + mt * 16 + ml) * 32 + qd * 8);
#pragma unroll
    for (int nt = 0; nt < 4; ++nt)
      b[nt] = *(const short8*)(Bs + (wn * 64 + nt * 16 + ml) * 32 + qd * 8);
#pragma unroll
    for (int mt = 0; mt < 4; ++mt)
#pragma unroll
      for (int nt = 0; nt < 4; ++nt) acc[mt][nt] = mfma_bf16(a[mt], b[nt], acc[mt][nt]);
  }
#pragma unroll
  for (int mt = 0; mt < 4; ++mt) {
#pragma unroll
    for (int nt = 0; nt < 4; ++nt) {
#pragma unroll
      for (int r = 0; r < 4; ++r) {
        int row = m0 + wm * 64 + mt * 16 + qd * 4 + r;
        int col = n0 + wn * 64 + nt * 16 + ml;
        if constexpr (CF32) {
          ((float*)Cp)[(size_t)row * ldc + col] = acc[mt][nt][r];
        } else {
          ((u16*)Cp)[(size_t)row * ldc + col] = f2bf(acc[mt][nt][r]);
        }
      }
    }
  }
#endif
}

// ---------------- fallback GEMM ----------------
template <bool AF32, bool BF32, bool CF32>
__global__ __launch_bounds__(256) void gemm_mixed(const void* __restrict__ Ap,
                                                  const void* __restrict__ Bp,
                                                  void* __restrict__ Cp,
                                                  int M, int N, int K,
                                                  int lda, int ldb, int ldc) {
#if defined(__HIP_DEVICE_COMPILE__)
  __shared__ u16 As[64][40];
  __shared__ u16 Bs[64][40];
  const int tid = threadIdx.x;
  const int lane = tid & 63;
  const int w = tid >> 6;
  const int m0 = blockIdx.y * 64;
  const int n0 = blockIdx.x * 64;
  const int arow = tid >> 2, acol = (tid & 3) * 8;
  const int brow = tid >> 3, bcol = (tid & 7) * 8;
  const int ml = lane & 15, qd = lane >> 4;
  float4v acc[4] = {};
  for (int kk = 0; kk < K; kk += 32) {
    __syncthreads();
    if constexpr (AF32) {
      const float* A = (const float*)Ap;
      const float* src = A + (size_t)(m0 + arow) * lda + (kk + acol);
      float4 f0 = *(const float4*)src;
      float4 f1 = *(const float4*)(src + 4);
      alignas(16) u16 tmp[8] = {f2bf(f0.x), f2bf(f0.y), f2bf(f0.z), f2bf(f0.w),
                                f2bf(f1.x), f2bf(f1.y), f2bf(f1.z), f2bf(f1.w)};
      *(uint4*)(&As[arow][acol]) = *(const uint4*)tmp;
    } else {
      const u16* A = (const u16*)Ap;
      *(uint4*)(&As[arow][acol]) = *(const uint4*)(A + (size_t)(m0 + arow) * lda + (kk + acol));
    }
    if constexpr (BF32) {
      const float* Bm = (const float*)Bp;
      const float* src = Bm + (size_t)(kk + brow) * ldb + (n0 + bcol);
      float4 f0 = *(const float4*)src;
      float4 f1 = *(const float4*)(src + 4);
      float fv[8] = {f0.x, f0.y, f0.z, f0.w, f1.x, f1.y, f1.z, f1.w};
#pragma unroll
      for (int i = 0; i < 8; ++i) Bs[bcol + i][brow] = f2bf(fv[i]);
    } else {
      const u16* Bm = (const u16*)Bp;
      uint4 bv = *(const uint4*)(Bm + (size_t)(kk + brow) * ldb + (n0 + bcol));
      const u16* bsp = (const u16*)&bv;
#pragma unroll
      for (int i = 0; i < 8; ++i) Bs[bcol + i][brow] = bsp[i];
    }
    __syncthreads();
    short8 af = *(const short8*)(&As[w * 16 + ml][qd * 8]);
#pragma unroll
    for (int nt = 0; nt < 4; ++nt) {
      short8 bf = *(const short8*)(&Bs[nt * 16 + ml][qd * 8]);
      acc[nt] = mfma_bf16(af, bf, acc[nt]);
    }
  }
#pragma unroll
  for (int nt = 0; nt < 4; ++nt) {
#pragma unroll
    for (int r = 0; r < 4; ++r) {
      int row = m0 + w * 16 + qd * 4 + r;
      int col = n0 + nt * 16 + ml;
      if constexpr (CF32) {
        ((float*)Cp)[(size_t)row * ldc + col] = acc[nt][r];
      } else {
        ((u16*)Cp)[(size_t)row * ldc + col] = f2bf(acc[nt][r]);
      }
    }
  }
#endif
}

// In-place RoPE on qkv [B,T,3C] bf16; q additionally scaled by qscale.
// (fallback path only; main path uses rope_vt)
__global__ __launch_bounds__(256) void rope_inplace(u16* __restrict__ qkv, float qscale) {
  int idx = blockIdx.x * 256 + threadIdx.x;
  int d = idx & 63;
  int h = (idx >> 6) & 15;
  int t = (idx >> 10) & 2047;
  int b = idx >> 21;
  size_t row = (size_t)(b * T_ + t) * LDQKV;
  u16* qp = qkv + row + h * 128;
  u16* kp = qkv + row + C_ + h * 128;
  float q1 = bfbits2f(qp[d]);
  float q2 = bfbits2f(qp[d + 64]);
  float k1 = bfbits2f(kp[d]);
  float k2 = bfbits2f(kp[d + 64]);
  float invf = exp2f((float)d * -0.20762050593046012f);
  float fr = (float)t * invf;
  float sn, cs;
  sincosf(fr, &sn, &cs);
  qp[d] = f2bf((q1 * cs - q2 * sn) * qscale);
  qp[d + 64] = f2bf((q2 * cs + q1 * sn) * qscale);
  kp[d] = f2bf(k1 * cs - k2 * sn);
  kp[d + 64] = f2bf(k2 * cs + k1 * sn);
}

// MFMA flash attention v6: single-buffered K/V staging, NATURAL VGPR.
// Occupancy free-option: LDS = 16K (kS) + 16K (vS) + 10K (pS) = 42 KiB
// -> LDS permits 3 blocks/CU; whether 3 materialize is decided by natural
// VGPR (~150-170). If VGPR <= ~168: 12 waves/CU (+50% latency hiding).
// If not: identical to the round-2 single-buf config, measured EQUAL to
// dbuf (281.7 vs 282.2 rest) -> no downside. Keeps (256,2) bound — round-7
// showed forcing (256,3) caps VGPR at 84 -> spills (attn 161us). Flow per
// chunk: barrier -> STAGE -> vmcnt(0) -> barrier -> compute.
// MEASURED-NEGATIVE variants (do not re-add without within-probe A/B):
//   exp2-domain/defer-max/setprio (-18us, r5); forced bounds(256,3) (r7).
__global__ __launch_bounds__(256, 2) void attn_fwd2(u16* __restrict__ qkv,
                                                    const u16* __restrict__ Vt) {
#if defined(__HIP_DEVICE_COMPILE__)
  __shared__ alignas(16) u16 kS[64 * 128];   // [key][d], swizzled slots
  __shared__ alignas(16) u16 vS[128 * 64];   // [d][key], swizzled slots
  __shared__ alignas(16) u16 pS[4][32][40];  // per-wave P [q][32 keys], +8 pad
  const int tid = threadIdx.x;
  const int lane = tid & 63;
  const int w = tid >> 6;
  const int ml = lane & 15, qd = lane >> 4;
  const int gx = blockIdx.x;
  const int half = gx >> 8, rem = gx & 255;
  const int bh = rem >> 3, q3 = rem & 7;
  const int qt = half ? q3 : (15 - q3);  // pair long+short tiles across halves
  const int b = bh >> 4, h = bh & 15;
  const int hc = h * 128;
  const int m0 = qt * 128;
  const size_t rb = (size_t)(b * T_);
  // Q B-frags in registers for whole block: qf[qtile][k4]; lane n=ml -> q-row
  short8 qf[2][4];
#pragma unroll
  for (int m = 0; m < 2; ++m) {
    const u16* qp = qkv + (rb + m0 + w * 32 + m * 16 + ml) * LDQKV + hc;
#pragma unroll
    for (int k4 = 0; k4 < 4; ++k4) qf[m][k4] = *(const short8*)(qp + k4 * 32 + qd * 8);
  }
  float4v acc[2][8] = {};
  float mi[2] = {-1.0e30f, -1.0e30f}, li[2] = {0.f, 0.f};
  const int nchunk = 2 * qt + 2;
  // staging decode (closed forms)
  const int krow0 = w * 16 + qd;                    // + i*4
  const int vd0 = w * 32 + (lane >> 3);             // + i*8
  const int vsegoff = ((lane & 7) ^ (lane >> 3)) * 8;
  const size_t vtbase = ((size_t)bh * 128) * 2048;

#define STAGE(cc)                                                            \
  do {                                                                       \
    _Pragma("unroll") for (int i_ = 0; i_ < 4; ++i_) {                       \
      int key_ = krow0 + i_ * 4;                                             \
      int seg_ = (ml ^ (i_ * 4 + qd)) * 8;                                   \
      async16(kS + (w * 4 + i_) * 512,                                       \
              qkv + (rb + (cc) * 64 + key_) * LDQKV + C_ + hc + seg_);       \
    }                                                                        \
    _Pragma("unroll") for (int i_ = 0; i_ < 4; ++i_) {                       \
      int d_ = vd0 + i_ * 8;                                                 \
      async16(vS + (w * 4 + i_) * 512,                                       \
              Vt + vtbase + (size_t)d_ * 2048 + (cc) * 64 + vsegoff);        \
    }                                                                        \
  } while (0)

  for (int c = 0; c < nchunk; ++c) {
    // all waves done reading the previous chunk before overwrite
    __syncthreads();
    STAGE(c);
    asm volatile("s_waitcnt vmcnt(0)" ::: "memory");
    __syncthreads();
    if (c * 64 > m0 + w * 32 + 31) continue;  // all keys future for this wave
    // ---- S^T = K Q^T : s[kt][qtile], C row=key(qd*4+r), col=q(ml) ----
    float4v s[4][2] = {};
#pragma unroll
    for (int kt = 0; kt < 4; ++kt) {
#pragma unroll
      for (int k4 = 0; k4 < 4; ++k4) {
        short8 kf = *(const short8*)(kS + ((kt * 16 + ml) * 16 + ((k4 * 4 + qd) ^ ml)) * 8);
        s[kt][0] = mfma_bf16(kf, qf[0][k4], s[kt][0]);
        s[kt][1] = mfma_bf16(kf, qf[1][k4], s[kt][1]);
      }
    }
    const bool domask = (c * 64 + 63) > (m0 + w * 32);
    float alpha[2];
#pragma unroll
    for (int m = 0; m < 2; ++m) {
      int qrow = m0 + w * 32 + m * 16 + ml;
      if (domask) {
#pragma unroll
        for (int kt = 0; kt < 4; ++kt)
#pragma unroll
          for (int r = 0; r < 4; ++r) {
            int key = c * 64 + kt * 16 + qd * 4 + r;
            if (key > qrow) s[kt][m][r] = -1.0e30f;
          }
      }
      float mx = -1.0e30f;
#pragma unroll
      for (int kt = 0; kt < 4; ++kt)
#pragma unroll
        for (int r = 0; r < 4; ++r) mx = fmaxf(mx, s[kt][m][r]);
      mx = fmaxf(mx, __shfl_xor(mx, 16, 64));
      mx = fmaxf(mx, __shfl_xor(mx, 32, 64));
      float mnew = fmaxf(mi[m], mx);
      float a = __expf(mi[m] - mnew);
      float sm = 0.f;
#pragma unroll
      for (int kt = 0; kt < 4; ++kt)
#pragma unroll
        for (int r = 0; r < 4; ++r) {
          float p = __expf(s[kt][m][r] - mnew);
          s[kt][m][r] = p;
          sm += p;
        }
      sm += __shfl_xor(sm, 16, 64);
      sm += __shfl_xor(sm, 32, 64);
      li[m] = li[m] * a + sm;
      mi[m] = mnew;
      alpha[m] = a;
    }
    // rescale O (alpha lives at lane ml=q'; broadcast to rows qd*4+r)
#pragma unroll
    for (int m = 0; m < 2; ++m) {
#pragma unroll
      for (int r = 0; r < 4; ++r) {
        float aq = __shfl(alpha[m], qd * 4 + r, 64);
#pragma unroll
        for (int dt = 0; dt < 8; ++dt) acc[m][dt][r] *= aq;
      }
    }
    // ---- O += P V, in two 32-key halves through the small pS buffer ----
#pragma unroll
    for (int k2 = 0; k2 < 2; ++k2) {
#pragma unroll
      for (int m = 0; m < 2; ++m) {
#pragma unroll
        for (int ktl = 0; ktl < 2; ++ktl) {
          int kt = k2 * 2 + ktl;
          uint2 pk;
          pk.x = pack2bf(s[kt][m][0], s[kt][m][1]);
          pk.y = pack2bf(s[kt][m][2], s[kt][m][3]);
          *(uint2*)&pS[w][m * 16 + ml][ktl * 16 + qd * 4] = pk;
        }
      }
      short8 pa0 = *(const short8*)&pS[w][ml][qd * 8];
      short8 pa1 = *(const short8*)&pS[w][16 + ml][qd * 8];
#pragma unroll
      for (int dt = 0; dt < 8; ++dt) {
        int d = dt * 16 + ml;
        short8 vf = *(const short8*)(vS + (d * 8 + ((k2 * 4 + qd) ^ (ml & 7))) * 8);
        acc[0][dt] = mfma_bf16(pa0, vf, acc[0][dt]);
        acc[1][dt] = mfma_bf16(pa1, vf, acc[1][dt]);
      }
    }
  }
#undef STAGE
  // ---- epilogue: O/l -> Q cols of qkv ----
#pragma unroll
  for (int m = 0; m < 2; ++m) {
#pragma unroll
    for (int r = 0; r < 4; ++r) {
      float inv = 1.0f / __shfl(li[m], qd * 4 + r, 64);
      size_t row = rb + m0 + w * 32 + m * 16 + qd * 4 + r;
#pragma unroll
      for (int dt = 0; dt < 8; ++dt)
        qkv[row * LDQKV + hc + dt * 16 + ml] = f2bf(acc[m][dt][r] * inv);
    }
  }
#endif
}

// Old flash attention (fallback path; expects unscaled Q).
__global__ __launch_bounds__(256, 2) void attn_fwd(u16* __restrict__ qkv) {
#if defined(__HIP_DEVICE_COMPILE__)
  __shared__ alignas(16) u16 ks[64][136];
  __shared__ alignas(16) u16 vt[128][72];
  __shared__ alignas(16) u16 pb[4][32][72];
  const int tid = threadIdx.x;
  const int lane = tid & 63;
  const int w = tid >> 6;
  const int ml = lane & 15, qd = lane >> 4;
  const int gx = blockIdx.x;
  const int half = gx >> 8;
  const int rem = gx & 255;
  const int bh = rem >> 3;
  const int q3 = rem & 7;
  const int qt = half ? q3 : (15 - q3);
  const int b = bh >> 4, h = bh & 15;
  const int hc = h * 128;
  const int m0 = qt * 128;
  const size_t rb = (size_t)(b * T_);
  short8 qf[2][4];
#pragma unroll
  for (int m = 0; m < 2; ++m) {
    const u16* qp = qkv + (rb + m0 + w * 32 + m * 16 + ml) * LDQKV + hc;
#pragma unroll
    for (int k4 = 0; k4 < 4; ++k4) qf[m][k4] = *(const short8*)(qp + k4 * 32 + qd * 8);
  }
  float4v acc[2][8] = {};
  float mi[2][4], li[2][4];
#pragma unroll
  for (int m = 0; m < 2; ++m)
#pragma unroll
    for (int r = 0; r < 4; ++r) { mi[m][r] = -1.0e30f; li[m][r] = 0.f; }
  const float scale = 0.08838834764831845f;
  const int srow = tid >> 2;
  const int scol = (tid & 3) * 32;
  const int nchunk = 2 * qt + 2;
  for (int c = 0; c < nchunk; ++c) {
    __syncthreads();
    {
      const u16* kp = qkv + (rb + c * 64 + srow) * LDQKV + C_ + hc + scol;
      const u16* vp = qkv + (rb + c * 64 + srow) * LDQKV + 2 * C_ + hc + scol;
#pragma unroll
      for (int i = 0; i < 4; ++i)
        *(uint4*)&ks[srow][scol + i * 8] = *(const uint4*)(kp + i * 8);
#pragma unroll
      for (int i = 0; i < 4; ++i) {
        uint4 vv = *(const uint4*)(vp + i * 8);
        const u16* e = (const u16*)&vv;
#pragma unroll
        for (int t = 0; t < 8; ++t) vt[scol + i * 8 + t][srow] = e[t];
      }
    }
    __syncthreads();
    if (c * 64 > m0 + w * 32 + 31) continue;
    float4v s[2][4] = {};
#pragma unroll
    for (int t = 0; t < 4; ++t) {
#pragma unroll
      for (int k4 = 0; k4 < 4; ++k4) {
        short8 bf = *(const short8*)(&ks[t * 16 + ml][k4 * 32 + qd * 8]);
        s[0][t] = mfma_bf16(qf[0][k4], bf, s[0][t]);
        s[1][t] = mfma_bf16(qf[1][k4], bf, s[1][t]);
      }
    }
    const bool domask = (c * 64 + 63) > (m0 + w * 32);
#pragma unroll
    for (int m = 0; m < 2; ++m) {
      float al[4];
#pragma unroll
      for (int r = 0; r < 4; ++r) {
        float x0 = s[m][0][r] * scale;
        float x1 = s[m][1][r] * scale;
        float x2 = s[m][2][r] * scale;
        float x3 = s[m][3][r] * scale;
        if (domask) {
          int row = m0 + w * 32 + m * 16 + qd * 4 + r;
          int j0 = c * 64 + ml;
          if (j0 > row) x0 = -1.0e30f;
          if (j0 + 16 > row) x1 = -1.0e30f;
          if (j0 + 32 > row) x2 = -1.0e30f;
          if (j0 + 48 > row) x3 = -1.0e30f;
        }
        float mx = fmaxf(fmaxf(x0, x1), fmaxf(x2, x3));
        mx = fmaxf(mx, __shfl_xor(mx, 1));
        mx = fmaxf(mx, __shfl_xor(mx, 2));
        mx = fmaxf(mx, __shfl_xor(mx, 4));
        mx = fmaxf(mx, __shfl_xor(mx, 8));
        float mnew = fmaxf(mi[m][r], mx);
        float a = __expf(mi[m][r] - mnew);
        float p0 = __expf(x0 - mnew);
        float p1 = __expf(x1 - mnew);
        float p2 = __expf(x2 - mnew);
        float p3 = __expf(x3 - mnew);
        float sm = p0 + p1 + p2 + p3;
        sm += __shfl_xor(sm, 1);
        sm += __shfl_xor(sm, 2);
        sm += __shfl_xor(sm, 4);
        sm += __shfl_xor(sm, 8);
        li[m][r] = li[m][r] * a + sm;
        mi[m][r] = mnew;
        al[r] = a;
        int prow = m * 16 + qd * 4 + r;
        pb[w][prow][ml] = f2bf(p0);
        pb[w][prow][16 + ml] = f2bf(p1);
        pb[w][prow][32 + ml] = f2bf(p2);
        pb[w][prow][48 + ml] = f2bf(p3);
      }
#pragma unroll
      for (int d = 0; d < 8; ++d) {
        acc[m][d][0] *= al[0];
        acc[m][d][1] *= al[1];
        acc[m][d][2] *= al[2];
        acc[m][d][3] *= al[3];
      }
    }
#pragma unroll
    for (int k2 = 0; k2 < 2; ++k2) {
      short8 pa0 = *(const short8*)(&pb[w][ml][k2 * 32 + qd * 8]);
      short8 pa1 = *(const short8*)(&pb[w][16 + ml][k2 * 32 + qd * 8]);
#pragma unroll
      for (int d = 0; d < 8; ++d) {
        short8 vf = *(const short8*)(&vt[d * 16 + ml][k2 * 32 + qd * 8]);
        acc[0][d] = mfma_bf16(pa0, vf, acc[0][d]);
        acc[1][d] = mfma_bf16(pa1, vf, acc[1][d]);
      }
    }
  }
#pragma unroll
  for (int m = 0; m < 2; ++m) {
#pragma unroll
    for (int r = 0; r < 4; ++r) {
      float inv = 1.0f / li[m][r];
      size_t row = rb + m0 + w * 32 + m * 16 + qd * 4 + r;
#pragma unroll
      for (int d = 0; d < 8; ++d)
        qkv[row * LDQKV + hc + d * 16 + ml] = f2bf(acc[m][d][r] * inv);
    }
  }
#endif
}

extern "C" void kernel_launch(void* const* d_in, const int* in_sizes, int n_in,
                              void* d_out, int out_size, void* d_ws, size_t ws_size,
                              hipStream_t stream) {
  const float* x = (const float*)d_in[0];     // [B,T,C] fp32
  const float* wqkv = (const float*)d_in[1];  // [C,3C] fp32
  const float* wout = (const float*)d_in[2];  // [C,C] fp32
  float* out = (float*)d_out;                 // [B,T,C] fp32
  char* ws = (char*)d_ws;
  u16* qkv = (u16*)ws;  // [4096, 6144] bf16 = 48 MB; Q cols reused as Y

  const size_t MB = 1024 * 1024;
  if (ws_size >= 96 * MB) {
    u16* xb = (u16*)(ws + 48 * MB);     // [4096,2048] bf16, 16 MB
    u16* wqkvT = (u16*)(ws + 64 * MB);  // [6144,2048] bf16, 24 MB
    u16* Vt = (u16*)(ws + 64 * MB);     // [32,128,2048] bf16, 16 MB (reuses wqkvT after GEMM1)
    u16* woutT = (u16*)(ws + 88 * MB);  // [2048,2048] bf16, 8 MB
    // merged pre-casts: x->xb, wqkv->wqkvT, wout->woutT (one launch)
    prep_all<<<dim3(24576), dim3(256), 0, stream>>>(x, xb, wqkv, wqkvT, wout, woutT);
    // GEMM1: 256x256 8-phase pipeline; grid = (4096/256)*(6144/256) = 384 (%8==0)
    gemm256_bt<false><<<dim3(384), dim3(512), 0, stream>>>(
        xb, wqkvT, qkv, 2048, 2048, 2048, 6144, 24);
    // merged rope (q scaled by 1/sqrt(D)) + Vt build (one launch)
    rope_vt<<<dim3(18432), dim3(256), 0, stream>>>(qkv, Vt, 0.08838834764831845f);
    attn_fwd2<<<dim3(512), dim3(256), 0, stream>>>(qkv, Vt);
    // GEMM2: 1D grid 512 (= 32 row-tiles x 16 col-tiles), XCD-swizzled
    gemm_bt<true><<<dim3(512), dim3(256), 0, stream>>>(
        qkv, woutT, out, 2048, 6144, 2048, 2048, 16);
  } else {
    gemm_mixed<true, true, false><<<dim3(96, 64), dim3(256), 0, stream>>>(
        x, wqkv, qkv, 4096, 6144, 2048, 2048, 6144, 6144);
    rope_inplace<<<dim3(16384), dim3(256), 0, stream>>>(qkv, 1.0f);
    attn_fwd<<<dim3(512), dim3(256), 0, stream>>>(qkv);
    gemm_mixed<false, true, true><<<dim3(32, 64), dim3(256), 0, stream>>>(
        qkv, wout, out, 4096, 2048, 2048, 6144, 2048, 2048);
  }
}